// Round 5
// baseline (692.527 us; speedup 1.0000x reference)
//
#include <hip/hip_runtime.h>
#include <hip/hip_bf16.h>
#include <math.h>

typedef __hip_bfloat16 bf16;
using f32x4  = __attribute__((ext_vector_type(4))) float;
using f32x2  = __attribute__((ext_vector_type(2))) float;
using bf16x8 = __attribute__((ext_vector_type(8))) short;

constexpr int BS = 2, NQ = 22223, MROWS = 44446;
constexpr int LH[4] = {100, 50, 25, 13};
constexpr int LW[4] = {167, 84, 42, 21};
constexpr int LSTART[4] = {0, 16700, 20900, 21950};
// Padded levels: +1 left/top, +2 right/bottom (Wp=W+3, Hp=H+3)
constexpr int PLW[4] = {170, 87, 45, 24};
constexpr int PLSTART[4] = {0, 17510, 22121, 23381};
constexpr int PTOT = 23765;

constexpr int BM = 128, BK = 32;
constexpr int LDT = 40;               // LDS row stride (bf16): 80B
constexpr int GX = (MROWS + BM - 1) / BM;   // 348

// ---------------------------------------------------------------------------
__global__ __launch_bounds__(256) void prep_weights(
    const float* __restrict__ W_vp, const float* __restrict__ W_so,
    const float* __restrict__ W_aw, const float* __restrict__ W_op,
    const float* __restrict__ b_so, const float* __restrict__ b_aw,
    bf16* __restrict__ Wt_vp, bf16* __restrict__ Wt_cat,
    bf16* __restrict__ Wt_op, float* __restrict__ bcat)
{
    int i = blockIdx.x * 256 + threadIdx.x;
    if (i < 256 * 256) {
        int n = i >> 8, k = i & 255;
        Wt_vp[i] = __float2bfloat16(W_vp[k * 256 + n]);
        Wt_op[i] = __float2bfloat16(W_op[k * 256 + n]);
    }
    if (i < 384 * 256) {
        int n = i >> 8, k = i & 255;
        float v = (n < 256) ? W_so[k * 256 + n] : W_aw[k * 128 + (n - 256)];
        Wt_cat[i] = __float2bfloat16(v);
    }
    if (i < 384) bcat[i] = (i < 256) ? b_so[i] : b_aw[i - 256];
}

// Map flat value-row -> padded vproj pixel index
__device__ inline int pad_row_idx(int r) {
    int b = 0, pix = r;
    if (pix >= NQ) { b = 1; pix -= NQ; }
    int base;
    if (pix < LSTART[1])      { int rel = pix;             int y = rel / 167; int x = rel - y * 167; base = PLSTART[0] + (y + 1) * 170 + (x + 1); }
    else if (pix < LSTART[2]) { int rel = pix - LSTART[1]; int y = rel / 84;  int x = rel - y * 84;  base = PLSTART[1] + (y + 1) * 87  + (x + 1); }
    else if (pix < LSTART[3]) { int rel = pix - LSTART[2]; int y = rel / 42;  int x = rel - y * 42;  base = PLSTART[2] + (y + 1) * 45  + (x + 1); }
    else                      { int rel = pix - LSTART[3]; int y = rel / 21;  int x = rel - y * 21;  base = PLSTART[3] + (y + 1) * 24  + (x + 1); }
    return b * PTOT + base;
}

// ---------------------------------------------------------------------------
// Shared MFMA tile core: acc[4][4] (64x64 per wave) over K=256, BK=32.
// ---------------------------------------------------------------------------
template<bool A_BF16>
__device__ __forceinline__ void mfma_core(
    const void* __restrict__ Av, int lda, const bf16* __restrict__ Wt,
    int row0, int bn0, int M, bf16* As, bf16* Bs, f32x4 (&acc)[4][4])
{
    const int tid = threadIdx.x;
    const int lane = tid & 63;
    const int wv = tid >> 6;
    const int wm = (wv >> 1) * 64, wn = (wv & 1) * 64;
    const int l15 = lane & 15, l4 = lane >> 4;

#pragma unroll
    for (int m = 0; m < 4; ++m)
#pragma unroll
        for (int n = 0; n < 4; ++n) { acc[m][n][0]=0.f; acc[m][n][1]=0.f; acc[m][n][2]=0.f; acc[m][n][3]=0.f; }

    for (int k0 = 0; k0 < 256; k0 += BK) {
        __syncthreads();
#pragma unroll
        for (int t = 0; t < 2; ++t) {
            int idx = tid + t * 256;
            int r = idx >> 2, s = idx & 3;
            {
                int grow = row0 + r; if (grow >= M) grow = M - 1;
                bf16 tmp[8];
                if constexpr (A_BF16) {
                    const bf16* ap = (const bf16*)Av + (size_t)grow * lda + (k0 + s * 8);
                    *(uint4*)tmp = *(const uint4*)ap;
                } else {
                    const float* ap = (const float*)Av + (size_t)grow * lda + (k0 + s * 8);
                    f32x4 v0 = *(const f32x4*)ap;
                    f32x4 v1 = *(const f32x4*)(ap + 4);
#pragma unroll
                    for (int j = 0; j < 4; ++j) tmp[j] = __float2bfloat16(v0[j]);
#pragma unroll
                    for (int j = 0; j < 4; ++j) tmp[4 + j] = __float2bfloat16(v1[j]);
                }
                *(uint4*)&As[r * LDT + s * 8] = *(const uint4*)tmp;
            }
            *(uint4*)&Bs[r * LDT + s * 8] =
                *(const uint4*)(Wt + (size_t)(bn0 + r) * 256 + (k0 + s * 8));
        }
        __syncthreads();

        bf16x8 af[4], bfr[4];
#pragma unroll
        for (int m = 0; m < 4; ++m)
            af[m] = *(const bf16x8*)&As[(wm + m * 16 + l15) * LDT + l4 * 8];
#pragma unroll
        for (int n = 0; n < 4; ++n)
            bfr[n] = *(const bf16x8*)&Bs[(wn + n * 16 + l15) * LDT + l4 * 8];
#pragma unroll
        for (int m = 0; m < 4; ++m)
#pragma unroll
            for (int n = 0; n < 4; ++n)
                acc[m][n] = __builtin_amdgcn_mfma_f32_16x16x32_bf16(af[m], bfr[n], acc[m][n], 0, 0, 0);
    }
}

// ---------------------------------------------------------------------------
// Fused producer GEMM: 5 N-slices per row-panel (3 offawl + 2 vproj-scatter),
// slice-fastest linearization + bijective chunked XCD swizzle for L2 reuse.
// ---------------------------------------------------------------------------
__global__ __launch_bounds__(256) void gemm_producer(
    const float* __restrict__ query, const float* __restrict__ value,
    const bf16* __restrict__ Wt_cat, const bf16* __restrict__ Wt_vp,
    const float* __restrict__ bcat, const float* __restrict__ bvp,
    bf16* __restrict__ offawl, bf16* __restrict__ vproj)
{
    __shared__ bf16 As[BM * LDT];
    __shared__ bf16 Bs[BM * LDT];

    constexpr int NWG = GX * 5;                 // 1740
    constexpr int QXW = NWG / 8, RXW = NWG % 8; // 217, 4
    int orig = blockIdx.x;
    int xcd = orig & 7, seq = orig >> 3;
    int swz = (xcd < RXW ? xcd * (QXW + 1) : RXW * (QXW + 1) + (xcd - RXW) * QXW) + seq;
    int slice = swz % 5;
    int row0 = (swz / 5) * BM;

    const bool isOff = slice < 3;
    const void* A = isOff ? (const void*)query : (const void*)value;
    const bf16* Wt = isOff ? Wt_cat : Wt_vp;
    const float* bias = isOff ? bcat : bvp;
    int bn0 = isOff ? slice * 128 : (slice - 3) * 128;

    f32x4 acc[4][4];
    mfma_core<false>(A, 256, Wt, row0, bn0, MROWS, As, Bs, acc);

    const int lane = threadIdx.x & 63;
    const int wv = threadIdx.x >> 6;
    const int wm = (wv >> 1) * 64, wn = (wv & 1) * 64;
    const int l15 = lane & 15, l4 = lane >> 4;

    if (isOff) {
#pragma unroll
        for (int m = 0; m < 4; ++m)
#pragma unroll
            for (int j = 0; j < 4; ++j) {
                int r = row0 + wm + m * 16 + l4 * 4 + j;
                if (r < MROWS) {
                    bf16* orow = offawl + (size_t)r * 384;
#pragma unroll
                    for (int n = 0; n < 4; ++n) {
                        int fcol = bn0 + wn + n * 16 + l15;
                        orow[fcol] = __float2bfloat16(acc[m][n][j] + bias[fcol]);
                    }
                }
            }
    } else {
#pragma unroll
        for (int m = 0; m < 4; ++m)
#pragma unroll
            for (int j = 0; j < 4; ++j) {
                int r = row0 + wm + m * 16 + l4 * 4 + j;
                if (r < MROWS) {
                    bf16* orow = vproj + (size_t)pad_row_idx(r) * 256;
#pragma unroll
                    for (int n = 0; n < 4; ++n) {
                        int fcol = bn0 + wn + n * 16 + l15;
                        orow[fcol] = __float2bfloat16(acc[m][n][j] + bias[fcol]);
                    }
                }
            }
    }
}

// ---------------------------------------------------------------------------
// Output GEMM: out = msda(bf16, ld 384) @ W_op^T + b_op + query. Linear grid,
// N-fastest + XCD swizzle (696 % 8 == 0).
// ---------------------------------------------------------------------------
__global__ __launch_bounds__(256) void gemm_out(
    const bf16* __restrict__ msda, const bf16* __restrict__ Wt_op,
    const float* __restrict__ b_op, const float* __restrict__ query,
    float* __restrict__ out)
{
    __shared__ bf16 As[BM * LDT];
    __shared__ bf16 Bs[BM * LDT];

    constexpr int NWG = GX * 2;  // 696
    int orig = blockIdx.x;
    int swz = (orig & 7) * (NWG / 8) + (orig >> 3);
    int bn0 = (swz & 1) * 128;
    int row0 = (swz >> 1) * BM;

    f32x4 acc[4][4];
    mfma_core<true>(msda, 384, Wt_op, row0, bn0, MROWS, As, Bs, acc);

    const int lane = threadIdx.x & 63;
    const int wv = threadIdx.x >> 6;
    const int wm = (wv >> 1) * 64, wn = (wv & 1) * 64;
    const int l15 = lane & 15, l4 = lane >> 4;

#pragma unroll
    for (int m = 0; m < 4; ++m)
#pragma unroll
        for (int j = 0; j < 4; ++j) {
            int r = row0 + wm + m * 16 + l4 * 4 + j;
            if (r < MROWS) {
#pragma unroll
                for (int n = 0; n < 4; ++n) {
                    int fcol = bn0 + wn + n * 16 + l15;
                    out[(size_t)r * 256 + fcol] =
                        acc[m][n][j] + b_op[fcol] + query[(size_t)r * 256 + fcol];
                }
            }
        }
}

// ---------------------------------------------------------------------------
// MSDA sampling v5: 1 lane per (query,head) — 8 queries per wave, 32 per block.
// Lane owns all 32 channels of its head (16 f32x2 accumulators). No LDS, no
// barrier. msda (bf16) written over the off-portion of the lane's own offawl
// row (read-before-write within the same lane => safe).
// ---------------------------------------------------------------------------
__device__ inline f32x2 bfpair(unsigned u) {
    f32x2 r;
    r.x = __uint_as_float(u << 16);
    r.y = __uint_as_float(u & 0xffff0000u);
    return r;
}

#define ACCU(U, B, WT) { f32x2 wv2 = {WT, WT};                       \
    acc[B+0] += bfpair(U.x) * wv2; acc[B+1] += bfpair(U.y) * wv2;    \
    acc[B+2] += bfpair(U.z) * wv2; acc[B+3] += bfpair(U.w) * wv2; }

__global__ __launch_bounds__(256) void msda_sample5(
    const bf16* __restrict__ vproj,      // padded layout [2*PTOT][256]
    const bf16* __restrict__ offawl,     // [MROWS][384]
    const float* __restrict__ refp,
    bf16* __restrict__ msda_out)         // aliases offawl rows (stride 384)
{
    const int tid = threadIdx.x;
    const int lane = tid & 63;
    const int h = lane & 7;
    int q = blockIdx.x * 32 + (tid >> 6) * 8 + (lane >> 3);
    const bool alive = q < MROWS;
    if (!alive) q = MROWS - 1;
    const int b = (q >= NQ) ? 1 : 0;

    const bf16* row = offawl + (size_t)q * 384;
    const bf16* op = row + h * 32;
    uint4 o0 = *(const uint4*)(op);
    uint4 o1 = *(const uint4*)(op + 8);
    uint4 o2 = *(const uint4*)(op + 16);
    uint4 o3 = *(const uint4*)(op + 24);
    uint4 g0 = *(const uint4*)(row + 256 + h * 16);
    uint4 g1 = *(const uint4*)(row + 256 + h * 16 + 8);
    float4 rp0 = *(const float4*)(refp + (size_t)q * 8);
    float4 rp1 = *(const float4*)(refp + (size_t)q * 8 + 4);

    unsigned off16[16] = {o0.x,o0.y,o0.z,o0.w, o1.x,o1.y,o1.z,o1.w,
                          o2.x,o2.y,o2.z,o2.w, o3.x,o3.y,o3.z,o3.w};
    float refxy[8] = {rp0.x,rp0.y,rp0.z,rp0.w, rp1.x,rp1.y,rp1.z,rp1.w};

    float aw[16];
    {
        unsigned gu[8] = {g0.x,g0.y,g0.z,g0.w, g1.x,g1.y,g1.z,g1.w};
        float lg[16];
#pragma unroll
        for (int i = 0; i < 8; ++i) {
            f32x2 pp = bfpair(gu[i]);
            lg[2*i] = pp.x; lg[2*i+1] = pp.y;
        }
        float mx = lg[0];
#pragma unroll
        for (int i = 1; i < 16; ++i) mx = fmaxf(mx, lg[i]);
        float ssum = 0.f;
#pragma unroll
        for (int i = 0; i < 16; ++i) { aw[i] = __expf(lg[i] - mx); ssum += aw[i]; }
        float inv = 1.f / ssum;
#pragma unroll
        for (int i = 0; i < 16; ++i) aw[i] *= inv;
    }

    f32x2 acc[16];
#pragma unroll
    for (int i = 0; i < 16; ++i) acc[i] = f32x2{0.f, 0.f};

#pragma unroll
    for (int l = 0; l < 4; ++l) {
        const int W = LW[l], H = LH[l], Wp = PLW[l];
        const float xb = refxy[l*2+0] * (float)W + 0.5f;   // pad-coord base
        const float yb = refxy[l*2+1] * (float)H + 0.5f;
        const bf16* vl = vproj + ((size_t)(b * PTOT + PLSTART[l])) * 256 + h * 32;
#pragma unroll
        for (int p = 0; p < 4; ++p) {
            const int t = l * 4 + p;
            f32x2 ov = bfpair(off16[t]);
            float x = fminf(fmaxf(xb + ov.x, 0.f), (float)(W + 1));
            float y = fminf(fmaxf(yb + ov.y, 0.f), (float)(H + 1));
            float x0f = floorf(x), y0f = floorf(y);
            float lx = x - x0f, ly = y - y0f;
            int x0 = (int)x0f, y0 = (int)y0f;
            const bf16* p00 = vl + (size_t)((y0 * Wp + x0) * 256);
            const bf16* p10 = p00 + Wp * 256;
            float aww = aw[t];
            float wx0 = 1.f - lx;
            float wy0 = (1.f - ly) * aww, wy1 = ly * aww;
            float w00 = wx0 * wy0, w01 = lx * wy0;
            float w10 = wx0 * wy1, w11 = lx * wy1;

            {   // row y0: corners 00, 01
                uint4 ca = *(const uint4*)p00;
                uint4 cb = *(const uint4*)(p00 + 8);
                uint4 cc = *(const uint4*)(p00 + 16);
                uint4 cd = *(const uint4*)(p00 + 24);
                uint4 ea = *(const uint4*)(p00 + 256);
                uint4 eb = *(const uint4*)(p00 + 264);
                uint4 ec = *(const uint4*)(p00 + 272);
                uint4 ed = *(const uint4*)(p00 + 280);
                ACCU(ca, 0, w00) ACCU(cb, 4, w00) ACCU(cc, 8, w00) ACCU(cd, 12, w00)
                ACCU(ea, 0, w01) ACCU(eb, 4, w01) ACCU(ec, 8, w01) ACCU(ed, 12, w01)
            }
            {   // row y1: corners 10, 11
                uint4 ca = *(const uint4*)p10;
                uint4 cb = *(const uint4*)(p10 + 8);
                uint4 cc = *(const uint4*)(p10 + 16);
                uint4 cd = *(const uint4*)(p10 + 24);
                uint4 ea = *(const uint4*)(p10 + 256);
                uint4 eb = *(const uint4*)(p10 + 264);
                uint4 ec = *(const uint4*)(p10 + 272);
                uint4 ed = *(const uint4*)(p10 + 280);
                ACCU(ca, 0, w10) ACCU(cb, 4, w10) ACCU(cc, 8, w10) ACCU(cd, 12, w10)
                ACCU(ea, 0, w11) ACCU(eb, 4, w11) ACCU(ec, 8, w11) ACCU(ed, 12, w11)
            }
        }
    }

    if (alive) {
        bf16 ob[32];
#pragma unroll
        for (int i = 0; i < 16; ++i) {
            ob[2*i]   = __float2bfloat16(acc[i].x);
            ob[2*i+1] = __float2bfloat16(acc[i].y);
        }
        bf16* drow = msda_out + (size_t)q * 384 + h * 32;
        *(uint4*)(drow)      = *(const uint4*)(ob);
        *(uint4*)(drow + 8)  = *(const uint4*)(ob + 8);
        *(uint4*)(drow + 16) = *(const uint4*)(ob + 16);
        *(uint4*)(drow + 24) = *(const uint4*)(ob + 24);
    }
}

// ---------------------------------------------------------------------------
extern "C" void kernel_launch(void* const* d_in, const int* in_sizes, int n_in,
                              void* d_out, int out_size, void* d_ws, size_t ws_size,
                              hipStream_t stream) {
    const float* query = (const float*)d_in[0];
    const float* value = (const float*)d_in[1];
    const float* refp  = (const float*)d_in[2];
    const float* W_so  = (const float*)d_in[3];
    const float* b_so  = (const float*)d_in[4];
    const float* W_aw  = (const float*)d_in[5];
    const float* b_aw  = (const float*)d_in[6];
    const float* W_vp  = (const float*)d_in[7];
    const float* b_vp  = (const float*)d_in[8];
    const float* W_op  = (const float*)d_in[9];
    const float* b_op  = (const float*)d_in[10];
    float* out = (float*)d_out;

    // Workspace:
    //   offawl : bf16 MROWS*384 (34.1 MB) [off|awl]; msda aliased over rows
    //   vproj  : bf16 2*PTOT*256 (24.3 MB) zero-padded level layout
    //   weights: Wt_cat 384*256, Wt_vp/Wt_op 256*256 bf16, bcat 384 f32
    bf16* d_offawl = (bf16*)d_ws;
    bf16* d_vproj  = d_offawl + (size_t)MROWS * 384;
    bf16* d_wtcat  = d_vproj + (size_t)2 * PTOT * 256;
    bf16* d_wtvp   = d_wtcat + 384 * 256;
    bf16* d_wtop   = d_wtvp + 256 * 256;
    float* d_bcat  = (float*)(d_wtop + 256 * 256);

    prep_weights<<<384, 256, 0, stream>>>(W_vp, W_so, W_aw, W_op, b_so, b_aw,
                                          d_wtvp, d_wtcat, d_wtop, d_bcat);
    hipMemsetAsync(d_vproj, 0, (size_t)2 * PTOT * 256 * sizeof(bf16), stream);

    gemm_producer<<<GX * 5, 256, 0, stream>>>(
        query, value, d_wtcat, d_wtvp, d_bcat, b_vp, d_offawl, d_vproj);

    msda_sample5<<<(MROWS + 31) / 32, 256, 0, stream>>>(
        d_vproj, d_offawl, refp, d_offawl);

    gemm_out<<<GX * 2, 256, 0, stream>>>(d_offawl, d_wtop, b_op, query, out);
}

// Round 6
// 326.345 us; speedup vs baseline: 2.1221x; 2.1221x over previous
//
#include <hip/hip_runtime.h>
#include <hip/hip_bf16.h>
#include <math.h>

typedef __hip_bfloat16 bf16;
using f32x4  = __attribute__((ext_vector_type(4))) float;
using f32x2  = __attribute__((ext_vector_type(2))) float;
using bf16x8 = __attribute__((ext_vector_type(8))) short;

constexpr int BS = 2, NQ = 22223, MROWS = 44446;
constexpr int LH[4] = {100, 50, 25, 13};
constexpr int LW[4] = {167, 84, 42, 21};
constexpr int LSTART[4] = {0, 16700, 20900, 21950};
// Padded levels: +1 left/top, +2 right/bottom (Wp=W+3, Hp=H+3)
constexpr int PLW[4] = {170, 87, 45, 24};
constexpr int PLSTART[4] = {0, 17510, 22121, 23381};
constexpr int PTOT = 23765;

constexpr int BM = 128, BK = 32;
constexpr int LDT = 40;               // LDS row stride (bf16): 80B
constexpr int GX = (MROWS + BM - 1) / BM;   // 348

// ---------------------------------------------------------------------------
__global__ __launch_bounds__(256) void prep_weights(
    const float* __restrict__ W_vp, const float* __restrict__ W_so,
    const float* __restrict__ W_aw, const float* __restrict__ W_op,
    const float* __restrict__ b_so, const float* __restrict__ b_aw,
    bf16* __restrict__ Wt_vp, bf16* __restrict__ Wt_cat,
    bf16* __restrict__ Wt_op, float* __restrict__ bcat)
{
    int i = blockIdx.x * 256 + threadIdx.x;
    if (i < 256 * 256) {
        int n = i >> 8, k = i & 255;
        Wt_vp[i] = __float2bfloat16(W_vp[k * 256 + n]);
        Wt_op[i] = __float2bfloat16(W_op[k * 256 + n]);
    }
    if (i < 384 * 256) {
        int n = i >> 8, k = i & 255;
        float v = (n < 256) ? W_so[k * 256 + n] : W_aw[k * 128 + (n - 256)];
        Wt_cat[i] = __float2bfloat16(v);
    }
    if (i < 384) bcat[i] = (i < 256) ? b_so[i] : b_aw[i - 256];
}

// Map flat value-row -> padded vproj pixel index
__device__ inline int pad_row_idx(int r) {
    int b = 0, pix = r;
    if (pix >= NQ) { b = 1; pix -= NQ; }
    int base;
    if (pix < LSTART[1])      { int rel = pix;             int y = rel / 167; int x = rel - y * 167; base = PLSTART[0] + (y + 1) * 170 + (x + 1); }
    else if (pix < LSTART[2]) { int rel = pix - LSTART[1]; int y = rel / 84;  int x = rel - y * 84;  base = PLSTART[1] + (y + 1) * 87  + (x + 1); }
    else if (pix < LSTART[3]) { int rel = pix - LSTART[2]; int y = rel / 42;  int x = rel - y * 42;  base = PLSTART[2] + (y + 1) * 45  + (x + 1); }
    else                      { int rel = pix - LSTART[3]; int y = rel / 21;  int x = rel - y * 21;  base = PLSTART[3] + (y + 1) * 24  + (x + 1); }
    return b * PTOT + base;
}

// ---------------------------------------------------------------------------
// Shared MFMA tile core: acc[4][4] (64x64 per wave) over K=256, BK=32.
// ---------------------------------------------------------------------------
template<bool A_BF16>
__device__ __forceinline__ void mfma_core(
    const void* __restrict__ Av, int lda, const bf16* __restrict__ Wt,
    int row0, int bn0, int M, bf16* As, bf16* Bs, f32x4 (&acc)[4][4])
{
    const int tid = threadIdx.x;
    const int lane = tid & 63;
    const int wv = tid >> 6;
    const int wm = (wv >> 1) * 64, wn = (wv & 1) * 64;
    const int l15 = lane & 15, l4 = lane >> 4;

#pragma unroll
    for (int m = 0; m < 4; ++m)
#pragma unroll
        for (int n = 0; n < 4; ++n) { acc[m][n][0]=0.f; acc[m][n][1]=0.f; acc[m][n][2]=0.f; acc[m][n][3]=0.f; }

    for (int k0 = 0; k0 < 256; k0 += BK) {
        __syncthreads();
#pragma unroll
        for (int t = 0; t < 2; ++t) {
            int idx = tid + t * 256;
            int r = idx >> 2, s = idx & 3;
            {
                int grow = row0 + r; if (grow >= M) grow = M - 1;
                bf16 tmp[8];
                if constexpr (A_BF16) {
                    const bf16* ap = (const bf16*)Av + (size_t)grow * lda + (k0 + s * 8);
                    *(uint4*)tmp = *(const uint4*)ap;
                } else {
                    const float* ap = (const float*)Av + (size_t)grow * lda + (k0 + s * 8);
                    f32x4 v0 = *(const f32x4*)ap;
                    f32x4 v1 = *(const f32x4*)(ap + 4);
#pragma unroll
                    for (int j = 0; j < 4; ++j) tmp[j] = __float2bfloat16(v0[j]);
#pragma unroll
                    for (int j = 0; j < 4; ++j) tmp[4 + j] = __float2bfloat16(v1[j]);
                }
                *(uint4*)&As[r * LDT + s * 8] = *(const uint4*)tmp;
            }
            *(uint4*)&Bs[r * LDT + s * 8] =
                *(const uint4*)(Wt + (size_t)(bn0 + r) * 256 + (k0 + s * 8));
        }
        __syncthreads();

        bf16x8 af[4], bfr[4];
#pragma unroll
        for (int m = 0; m < 4; ++m)
            af[m] = *(const bf16x8*)&As[(wm + m * 16 + l15) * LDT + l4 * 8];
#pragma unroll
        for (int n = 0; n < 4; ++n)
            bfr[n] = *(const bf16x8*)&Bs[(wn + n * 16 + l15) * LDT + l4 * 8];
#pragma unroll
        for (int m = 0; m < 4; ++m)
#pragma unroll
            for (int n = 0; n < 4; ++n)
                acc[m][n] = __builtin_amdgcn_mfma_f32_16x16x32_bf16(af[m], bfr[n], acc[m][n], 0, 0, 0);
    }
}

// ---------------------------------------------------------------------------
// Fused producer GEMM: 5 N-slices per row-panel (3 offawl bf16 + 2 vproj f32
// padded-scatter), slice-fastest linearization + bijective XCD swizzle.
// ---------------------------------------------------------------------------
__global__ __launch_bounds__(256) void gemm_producer(
    const float* __restrict__ query, const float* __restrict__ value,
    const bf16* __restrict__ Wt_cat, const bf16* __restrict__ Wt_vp,
    const float* __restrict__ bcat, const float* __restrict__ bvp,
    bf16* __restrict__ offawl, float* __restrict__ vproj)
{
    __shared__ bf16 As[BM * LDT];
    __shared__ bf16 Bs[BM * LDT];

    constexpr int NWG = GX * 5;                 // 1740
    constexpr int QXW = NWG / 8, RXW = NWG % 8; // 217, 4
    int orig = blockIdx.x;
    int xcd = orig & 7, seq = orig >> 3;
    int swz = (xcd < RXW ? xcd * (QXW + 1) : RXW * (QXW + 1) + (xcd - RXW) * QXW) + seq;
    int slice = swz % 5;
    int row0 = (swz / 5) * BM;

    const bool isOff = slice < 3;
    const void* A = isOff ? (const void*)query : (const void*)value;
    const bf16* Wt = isOff ? Wt_cat : Wt_vp;
    const float* bias = isOff ? bcat : bvp;
    int bn0 = isOff ? slice * 128 : (slice - 3) * 128;

    f32x4 acc[4][4];
    mfma_core<false>(A, 256, Wt, row0, bn0, MROWS, As, Bs, acc);

    const int lane = threadIdx.x & 63;
    const int wv = threadIdx.x >> 6;
    const int wm = (wv >> 1) * 64, wn = (wv & 1) * 64;
    const int l15 = lane & 15, l4 = lane >> 4;

    if (isOff) {
#pragma unroll
        for (int m = 0; m < 4; ++m)
#pragma unroll
            for (int j = 0; j < 4; ++j) {
                int r = row0 + wm + m * 16 + l4 * 4 + j;
                if (r < MROWS) {
                    bf16* orow = offawl + (size_t)r * 384;
#pragma unroll
                    for (int n = 0; n < 4; ++n) {
                        int fcol = bn0 + wn + n * 16 + l15;
                        orow[fcol] = __float2bfloat16(acc[m][n][j] + bias[fcol]);
                    }
                }
            }
    } else {
#pragma unroll
        for (int m = 0; m < 4; ++m)
#pragma unroll
            for (int j = 0; j < 4; ++j) {
                int r = row0 + wm + m * 16 + l4 * 4 + j;
                if (r < MROWS) {
                    float* orow = vproj + (size_t)pad_row_idx(r) * 256;
#pragma unroll
                    for (int n = 0; n < 4; ++n) {
                        int fcol = bn0 + wn + n * 16 + l15;
                        orow[fcol] = acc[m][n][j] + bias[fcol];
                    }
                }
            }
    }
}

// ---------------------------------------------------------------------------
// Output GEMM: out = msda(bf16, ld 384) @ W_op^T + b_op + query.
// ---------------------------------------------------------------------------
__global__ __launch_bounds__(256) void gemm_out(
    const bf16* __restrict__ msda, const bf16* __restrict__ Wt_op,
    const float* __restrict__ b_op, const float* __restrict__ query,
    float* __restrict__ out)
{
    __shared__ bf16 As[BM * LDT];
    __shared__ bf16 Bs[BM * LDT];

    constexpr int NWG = GX * 2;  // 696
    int orig = blockIdx.x;
    int swz = (orig & 7) * (NWG / 8) + (orig >> 3);
    int bn0 = (swz & 1) * 128;
    int row0 = (swz >> 1) * BM;

    f32x4 acc[4][4];
    mfma_core<true>(msda, 384, Wt_op, row0, bn0, MROWS, As, Bs, acc);

    const int lane = threadIdx.x & 63;
    const int wv = threadIdx.x >> 6;
    const int wm = (wv >> 1) * 64, wn = (wv & 1) * 64;
    const int l15 = lane & 15, l4 = lane >> 4;

#pragma unroll
    for (int m = 0; m < 4; ++m)
#pragma unroll
        for (int j = 0; j < 4; ++j) {
            int r = row0 + wm + m * 16 + l4 * 4 + j;
            if (r < MROWS) {
#pragma unroll
                for (int n = 0; n < 4; ++n) {
                    int fcol = bn0 + wn + n * 16 + l15;
                    out[(size_t)r * 256 + fcol] =
                        acc[m][n][j] + b_op[fcol] + query[(size_t)r * 256 + fcol];
                }
            }
        }
}

// ---------------------------------------------------------------------------
// MSDA sampling v6 = R4 structure + fp32 vproj (no bf16 unpack in inner loop).
// 2 queries per wave, 8 per block; lane = qs*32 + h*4 + s owns 8 channels.
// ---------------------------------------------------------------------------
__device__ inline f32x2 bfpair(unsigned u) {
    f32x2 r;
    r.x = __uint_as_float(u << 16);
    r.y = __uint_as_float(u & 0xffff0000u);
    return r;
}

__global__ __launch_bounds__(256) void msda_sample6(
    const float* __restrict__ vproj,     // padded layout [2*PTOT][256] fp32
    const bf16* __restrict__ offawl,     // [MROWS][384] bf16
    const float* __restrict__ refp,
    bf16* __restrict__ msda_out)         // aliases offawl rows (stride 384)
{
    __shared__ uint2 sOA[8][128];        // 8 rows x 1024B (payload 768B)
    __shared__ float sRef[8][8];

    const int tid = threadIdx.x;
    const int q0 = blockIdx.x * 8;

#pragma unroll
    for (int k = 0; k < 4; ++k) {
        int idx = tid + k * 256;
        int row = idx >> 7, e = idx & 127;
        if (e < 96) {
            int grow = min(q0 + row, MROWS - 1);
            sOA[row][e] = *((const uint2*)(offawl + (size_t)grow * 384) + e);
        }
    }
    if (tid < 64) {
        int row = tid >> 3, er = tid & 7;
        int grow = min(q0 + row, MROWS - 1);
        sRef[row][er] = refp[(size_t)grow * 8 + er];
    }
    __syncthreads();

    const int w = tid >> 6;
    const int lane = tid & 63;
    const int qs = lane >> 5;
    const int h = (lane >> 2) & 7;
    const int s = lane & 3;
    const int qrow = w * 2 + qs;
    int q = q0 + qrow;
    const bool alive = q < MROWS;
    if (!alive) q = MROWS - 1;
    const int b = (q >= NQ) ? 1 : 0;

    const char* rowp = (const char*)&sOA[qrow][0];
    unsigned off16[16];
    {
        uint4 o0 = *(const uint4*)(rowp + h * 64);
        uint4 o1 = *(const uint4*)(rowp + h * 64 + 16);
        uint4 o2 = *(const uint4*)(rowp + h * 64 + 32);
        uint4 o3 = *(const uint4*)(rowp + h * 64 + 48);
        off16[0]=o0.x; off16[1]=o0.y; off16[2]=o0.z; off16[3]=o0.w;
        off16[4]=o1.x; off16[5]=o1.y; off16[6]=o1.z; off16[7]=o1.w;
        off16[8]=o2.x; off16[9]=o2.y; off16[10]=o2.z; off16[11]=o2.w;
        off16[12]=o3.x; off16[13]=o3.y; off16[14]=o3.z; off16[15]=o3.w;
    }

    float aw[16];
    {
        uint4 g0 = *(const uint4*)(rowp + 512 + h * 32);
        uint4 g1 = *(const uint4*)(rowp + 512 + h * 32 + 16);
        unsigned gu[8] = {g0.x,g0.y,g0.z,g0.w,g1.x,g1.y,g1.z,g1.w};
        float lg[16];
#pragma unroll
        for (int i = 0; i < 8; ++i) {
            f32x2 p = bfpair(gu[i]);
            lg[2*i] = p.x; lg[2*i+1] = p.y;
        }
        float mx = lg[0];
#pragma unroll
        for (int i = 1; i < 16; ++i) mx = fmaxf(mx, lg[i]);
        float ssum = 0.f;
#pragma unroll
        for (int i = 0; i < 16; ++i) { aw[i] = __expf(lg[i] - mx); ssum += aw[i]; }
        float inv = 1.f / ssum;
#pragma unroll
        for (int i = 0; i < 16; ++i) aw[i] *= inv;
    }

    f32x4 accA = {0.f,0.f,0.f,0.f}, accB = {0.f,0.f,0.f,0.f};

#pragma unroll
    for (int l = 0; l < 4; ++l) {
        const int W = LW[l], H = LH[l], Wp = PLW[l];
        const float xb = sRef[qrow][l * 2 + 0] * (float)W + 0.5f;   // pad-coord base
        const float yb = sRef[qrow][l * 2 + 1] * (float)H + 0.5f;
        const float* vl = vproj + ((size_t)(b * PTOT + PLSTART[l])) * 256 + h * 32 + s * 8;
#pragma unroll
        for (int p = 0; p < 4; ++p) {
            const int t = l * 4 + p;
            f32x2 o2 = bfpair(off16[t]);
            float x = fminf(fmaxf(xb + o2.x, 0.f), (float)(W + 1));
            float y = fminf(fmaxf(yb + o2.y, 0.f), (float)(H + 1));
            float x0f = floorf(x), y0f = floorf(y);
            float lx = x - x0f, ly = y - y0f;
            int x0 = (int)x0f, y0 = (int)y0f;
            const float* p00 = vl + (size_t)((y0 * Wp + x0) * 256);
            const float* p10 = p00 + Wp * 256;
            float aww = aw[t];
            float wx0 = 1.f - lx;
            float wy0 = (1.f - ly) * aww, wy1 = ly * aww;
            float w00 = wx0 * wy0, w01 = lx * wy0;
            float w10 = wx0 * wy1, w11 = lx * wy1;

#define CORNERF(PTR, WT) {                                   \
            f32x4 c0 = *(const f32x4*)(PTR);                 \
            f32x4 c1 = *(const f32x4*)((PTR) + 4);           \
            f32x4 wv4 = {WT, WT, WT, WT};                    \
            accA += c0 * wv4; accB += c1 * wv4; }
            CORNERF(p00, w00)
            CORNERF(p00 + 256, w01)
            CORNERF(p10, w10)
            CORNERF(p10 + 256, w11)
#undef CORNERF
        }
    }

    if (alive) {
        bf16 ob[8];
#pragma unroll
        for (int i = 0; i < 4; ++i) ob[i] = __float2bfloat16(accA[i]);
#pragma unroll
        for (int i = 0; i < 4; ++i) ob[4 + i] = __float2bfloat16(accB[i]);
        *(uint4*)(msda_out + (size_t)q * 384 + h * 32 + s * 8) = *(const uint4*)ob;
    }
}

// ---------------------------------------------------------------------------
extern "C" void kernel_launch(void* const* d_in, const int* in_sizes, int n_in,
                              void* d_out, int out_size, void* d_ws, size_t ws_size,
                              hipStream_t stream) {
    const float* query = (const float*)d_in[0];
    const float* value = (const float*)d_in[1];
    const float* refp  = (const float*)d_in[2];
    const float* W_so  = (const float*)d_in[3];
    const float* b_so  = (const float*)d_in[4];
    const float* W_aw  = (const float*)d_in[5];
    const float* b_aw  = (const float*)d_in[6];
    const float* W_vp  = (const float*)d_in[7];
    const float* b_vp  = (const float*)d_in[8];
    const float* W_op  = (const float*)d_in[9];
    const float* b_op  = (const float*)d_in[10];
    float* out = (float*)d_out;

    // Workspace:
    //   offawl : bf16 MROWS*384 (34.1 MB) [off|awl]; msda aliased over rows
    //   vproj  : f32 2*PTOT*256 (48.7 MB) zero-padded level layout
    //   weights: Wt_cat 384*256, Wt_vp/Wt_op 256*256 bf16, bcat 384 f32
    bf16*  d_offawl = (bf16*)d_ws;
    float* d_vproj  = (float*)(d_offawl + (size_t)MROWS * 384);
    bf16*  d_wtcat  = (bf16*)(d_vproj + (size_t)2 * PTOT * 256);
    bf16*  d_wtvp   = d_wtcat + 384 * 256;
    bf16*  d_wtop   = d_wtvp + 256 * 256;
    float* d_bcat   = (float*)(d_wtop + 256 * 256);

    prep_weights<<<384, 256, 0, stream>>>(W_vp, W_so, W_aw, W_op, b_so, b_aw,
                                          d_wtvp, d_wtcat, d_wtop, d_bcat);
    hipMemsetAsync(d_vproj, 0, (size_t)2 * PTOT * 256 * sizeof(float), stream);

    gemm_producer<<<GX * 5, 256, 0, stream>>>(
        query, value, d_wtcat, d_wtvp, d_bcat, b_vp, d_offawl, d_vproj);

    msda_sample6<<<(MROWS + 7) / 8, 256, 0, stream>>>(
        d_vproj, d_offawl, refp, d_offawl);

    gemm_out<<<GX * 2, 256, 0, stream>>>(d_offawl, d_wtop, b_op, query, out);
}

// Round 7
// 170.666 us; speedup vs baseline: 4.0578x; 1.9122x over previous
//
#include <hip/hip_runtime.h>
#include <hip/hip_bf16.h>
#include <math.h>

typedef __hip_bfloat16 bf16;
using f32x4  = __attribute__((ext_vector_type(4))) float;
using f32x2  = __attribute__((ext_vector_type(2))) float;
using bf16x8 = __attribute__((ext_vector_type(8))) short;
using f16x2  = __attribute__((ext_vector_type(2))) _Float16;

constexpr int BS = 2, NQ = 22223, MROWS = 44446;
constexpr int LH[4] = {100, 50, 25, 13};
constexpr int LW[4] = {167, 84, 42, 21};
constexpr int LSTART[4] = {0, 16700, 20900, 21950};
// Padded levels: +1 left/top, +2 right/bottom (Wp=W+3, Hp=H+3)
constexpr int PLW[4] = {170, 87, 45, 24};
constexpr int PLSTART[4] = {0, 17510, 22121, 23381};
constexpr int PTOT = 23765;

constexpr int BM = 128, BK = 32;
constexpr int LDT = 40;               // LDS row stride (bf16): 80B
constexpr int GX = (MROWS + BM - 1) / BM;   // 348

// ---------------------------------------------------------------------------
__global__ __launch_bounds__(256) void prep_weights(
    const float* __restrict__ W_vp, const float* __restrict__ W_so,
    const float* __restrict__ W_aw, const float* __restrict__ W_op,
    const float* __restrict__ b_so, const float* __restrict__ b_aw,
    bf16* __restrict__ Wt_vp, bf16* __restrict__ Wt_cat,
    bf16* __restrict__ Wt_op, float* __restrict__ bcat)
{
    int i = blockIdx.x * 256 + threadIdx.x;
    if (i < 256 * 256) {
        int n = i >> 8, k = i & 255;
        Wt_vp[i] = __float2bfloat16(W_vp[k * 256 + n]);
        Wt_op[i] = __float2bfloat16(W_op[k * 256 + n]);
    }
    if (i < 384 * 256) {
        int n = i >> 8, k = i & 255;
        float v = (n < 256) ? W_so[k * 256 + n] : W_aw[k * 128 + (n - 256)];
        Wt_cat[i] = __float2bfloat16(v);
    }
    if (i < 384) bcat[i] = (i < 256) ? b_so[i] : b_aw[i - 256];
}

// Map flat value-row -> padded vproj pixel index
__device__ inline int pad_row_idx(int r) {
    int b = 0, pix = r;
    if (pix >= NQ) { b = 1; pix -= NQ; }
    int base;
    if (pix < LSTART[1])      { int rel = pix;             int y = rel / 167; int x = rel - y * 167; base = PLSTART[0] + (y + 1) * 170 + (x + 1); }
    else if (pix < LSTART[2]) { int rel = pix - LSTART[1]; int y = rel / 84;  int x = rel - y * 84;  base = PLSTART[1] + (y + 1) * 87  + (x + 1); }
    else if (pix < LSTART[3]) { int rel = pix - LSTART[2]; int y = rel / 42;  int x = rel - y * 42;  base = PLSTART[2] + (y + 1) * 45  + (x + 1); }
    else                      { int rel = pix - LSTART[3]; int y = rel / 21;  int x = rel - y * 21;  base = PLSTART[3] + (y + 1) * 24  + (x + 1); }
    return b * PTOT + base;
}

// ---------------------------------------------------------------------------
// Shared MFMA tile core: acc[4][4] (64x64 per wave) over K=256, BK=32.
// ---------------------------------------------------------------------------
template<bool A_BF16>
__device__ __forceinline__ void mfma_core(
    const void* __restrict__ Av, int lda, const bf16* __restrict__ Wt,
    int row0, int bn0, int M, bf16* As, bf16* Bs, f32x4 (&acc)[4][4])
{
    const int tid = threadIdx.x;
    const int lane = tid & 63;
    const int wv = tid >> 6;
    const int wm = (wv >> 1) * 64, wn = (wv & 1) * 64;
    const int l15 = lane & 15, l4 = lane >> 4;

#pragma unroll
    for (int m = 0; m < 4; ++m)
#pragma unroll
        for (int n = 0; n < 4; ++n) { acc[m][n][0]=0.f; acc[m][n][1]=0.f; acc[m][n][2]=0.f; acc[m][n][3]=0.f; }

    for (int k0 = 0; k0 < 256; k0 += BK) {
        __syncthreads();
#pragma unroll
        for (int t = 0; t < 2; ++t) {
            int idx = tid + t * 256;
            int r = idx >> 2, s = idx & 3;
            {
                int grow = row0 + r; if (grow >= M) grow = M - 1;
                bf16 tmp[8];
                if constexpr (A_BF16) {
                    const bf16* ap = (const bf16*)Av + (size_t)grow * lda + (k0 + s * 8);
                    *(uint4*)tmp = *(const uint4*)ap;
                } else {
                    const float* ap = (const float*)Av + (size_t)grow * lda + (k0 + s * 8);
                    f32x4 v0 = *(const f32x4*)ap;
                    f32x4 v1 = *(const f32x4*)(ap + 4);
#pragma unroll
                    for (int j = 0; j < 4; ++j) tmp[j] = __float2bfloat16(v0[j]);
#pragma unroll
                    for (int j = 0; j < 4; ++j) tmp[4 + j] = __float2bfloat16(v1[j]);
                }
                *(uint4*)&As[r * LDT + s * 8] = *(const uint4*)tmp;
            }
            *(uint4*)&Bs[r * LDT + s * 8] =
                *(const uint4*)(Wt + (size_t)(bn0 + r) * 256 + (k0 + s * 8));
        }
        __syncthreads();

        bf16x8 af[4], bfr[4];
#pragma unroll
        for (int m = 0; m < 4; ++m)
            af[m] = *(const bf16x8*)&As[(wm + m * 16 + l15) * LDT + l4 * 8];
#pragma unroll
        for (int n = 0; n < 4; ++n)
            bfr[n] = *(const bf16x8*)&Bs[(wn + n * 16 + l15) * LDT + l4 * 8];
#pragma unroll
        for (int m = 0; m < 4; ++m)
#pragma unroll
            for (int n = 0; n < 4; ++n)
                acc[m][n] = __builtin_amdgcn_mfma_f32_16x16x32_bf16(af[m], bfr[n], acc[m][n], 0, 0, 0);
    }
}

// ---------------------------------------------------------------------------
// Fused producer GEMM: 5 N-slices per row-panel (3 offawl bf16 + 2 vproj fp16
// padded-scatter), slice-fastest linearization + bijective XCD swizzle.
// ---------------------------------------------------------------------------
__global__ __launch_bounds__(256) void gemm_producer(
    const float* __restrict__ query, const float* __restrict__ value,
    const bf16* __restrict__ Wt_cat, const bf16* __restrict__ Wt_vp,
    const float* __restrict__ bcat, const float* __restrict__ bvp,
    bf16* __restrict__ offawl, _Float16* __restrict__ vproj)
{
    __shared__ bf16 As[BM * LDT];
    __shared__ bf16 Bs[BM * LDT];

    constexpr int NWG = GX * 5;                 // 1740
    constexpr int QXW = NWG / 8, RXW = NWG % 8; // 217, 4
    int orig = blockIdx.x;
    int xcd = orig & 7, seq = orig >> 3;
    int swz = (xcd < RXW ? xcd * (QXW + 1) : RXW * (QXW + 1) + (xcd - RXW) * QXW) + seq;
    int slice = swz % 5;
    int row0 = (swz / 5) * BM;

    const bool isOff = slice < 3;
    const void* A = isOff ? (const void*)query : (const void*)value;
    const bf16* Wt = isOff ? Wt_cat : Wt_vp;
    const float* bias = isOff ? bcat : bvp;
    int bn0 = isOff ? slice * 128 : (slice - 3) * 128;

    f32x4 acc[4][4];
    mfma_core<false>(A, 256, Wt, row0, bn0, MROWS, As, Bs, acc);

    const int lane = threadIdx.x & 63;
    const int wv = threadIdx.x >> 6;
    const int wm = (wv >> 1) * 64, wn = (wv & 1) * 64;
    const int l15 = lane & 15, l4 = lane >> 4;

    if (isOff) {
#pragma unroll
        for (int m = 0; m < 4; ++m)
#pragma unroll
            for (int j = 0; j < 4; ++j) {
                int r = row0 + wm + m * 16 + l4 * 4 + j;
                if (r < MROWS) {
                    bf16* orow = offawl + (size_t)r * 384;
#pragma unroll
                    for (int n = 0; n < 4; ++n) {
                        int fcol = bn0 + wn + n * 16 + l15;
                        orow[fcol] = __float2bfloat16(acc[m][n][j] + bias[fcol]);
                    }
                }
            }
    } else {
#pragma unroll
        for (int m = 0; m < 4; ++m)
#pragma unroll
            for (int j = 0; j < 4; ++j) {
                int r = row0 + wm + m * 16 + l4 * 4 + j;
                if (r < MROWS) {
                    _Float16* orow = vproj + (size_t)pad_row_idx(r) * 256;
#pragma unroll
                    for (int n = 0; n < 4; ++n) {
                        int fcol = bn0 + wn + n * 16 + l15;
                        orow[fcol] = (_Float16)(acc[m][n][j] + bias[fcol]);
                    }
                }
            }
    }
}

// ---------------------------------------------------------------------------
// Output GEMM: out = msda(bf16, ld 384) @ W_op^T + b_op + query.
// ---------------------------------------------------------------------------
__global__ __launch_bounds__(256) void gemm_out(
    const bf16* __restrict__ msda, const bf16* __restrict__ Wt_op,
    const float* __restrict__ b_op, const float* __restrict__ query,
    float* __restrict__ out)
{
    __shared__ bf16 As[BM * LDT];
    __shared__ bf16 Bs[BM * LDT];

    constexpr int NWG = GX * 2;  // 696
    int orig = blockIdx.x;
    int swz = (orig & 7) * (NWG / 8) + (orig >> 3);
    int bn0 = (swz & 1) * 128;
    int row0 = (swz >> 1) * BM;

    f32x4 acc[4][4];
    mfma_core<true>(msda, 384, Wt_op, row0, bn0, MROWS, As, Bs, acc);

    const int lane = threadIdx.x & 63;
    const int wv = threadIdx.x >> 6;
    const int wm = (wv >> 1) * 64, wn = (wv & 1) * 64;
    const int l15 = lane & 15, l4 = lane >> 4;

#pragma unroll
    for (int m = 0; m < 4; ++m)
#pragma unroll
        for (int j = 0; j < 4; ++j) {
            int r = row0 + wm + m * 16 + l4 * 4 + j;
            if (r < MROWS) {
#pragma unroll
                for (int n = 0; n < 4; ++n) {
                    int fcol = bn0 + wn + n * 16 + l15;
                    out[(size_t)r * 256 + fcol] =
                        acc[m][n][j] + b_op[fcol] + query[(size_t)r * 256 + fcol];
                }
            }
        }
}

// ---------------------------------------------------------------------------
// MSDA sampling v7 = R4 structure + fp16 vproj (packed v_pk_fma_f16 accum)
// + bijective XCD-swizzled block->query mapping (each XCD owns a contiguous
// query range -> its L2 touches ~1/8 of the pyramid instead of all of it).
// 2 queries per wave, 8 per block; lane = qs*32 + h*4 + s owns 8 channels.
// ---------------------------------------------------------------------------
__device__ inline f32x2 bfpair(unsigned u) {
    f32x2 r;
    r.x = __uint_as_float(u << 16);
    r.y = __uint_as_float(u & 0xffff0000u);
    return r;
}

__global__ __launch_bounds__(256) void msda_sample7(
    const _Float16* __restrict__ vproj,  // padded layout [2*PTOT][256] fp16
    const bf16* __restrict__ offawl,     // [MROWS][384] bf16
    const float* __restrict__ refp,
    bf16* __restrict__ msda_out)         // aliases offawl rows (stride 384)
{
    __shared__ uint2 sOA[8][128];        // 8 rows x 1024B (payload 768B)
    __shared__ float sRef[8][8];

    // bijective XCD swizzle (m204 formula)
    constexpr int NBLK = (MROWS + 7) / 8;        // 5556
    constexpr int QX = NBLK / 8, RX = NBLK % 8;  // 694, 4
    const int orig = blockIdx.x;
    const int xcd = orig & 7, seq = orig >> 3;
    const int blk = (xcd < RX ? xcd * (QX + 1) : RX * (QX + 1) + (xcd - RX) * QX) + seq;
    const int q0 = blk * 8;

    const int tid = threadIdx.x;

#pragma unroll
    for (int k = 0; k < 4; ++k) {
        int idx = tid + k * 256;
        int row = idx >> 7, e = idx & 127;
        if (e < 96) {
            int grow = min(q0 + row, MROWS - 1);
            sOA[row][e] = *((const uint2*)(offawl + (size_t)grow * 384) + e);
        }
    }
    if (tid < 64) {
        int row = tid >> 3, er = tid & 7;
        int grow = min(q0 + row, MROWS - 1);
        sRef[row][er] = refp[(size_t)grow * 8 + er];
    }
    __syncthreads();

    const int w = tid >> 6;
    const int lane = tid & 63;
    const int qs = lane >> 5;
    const int h = (lane >> 2) & 7;
    const int s = lane & 3;
    const int qrow = w * 2 + qs;
    int q = q0 + qrow;
    const bool alive = q < MROWS;
    if (!alive) q = MROWS - 1;
    const int b = (q >= NQ) ? 1 : 0;

    const char* rowp = (const char*)&sOA[qrow][0];
    unsigned off16[16];
    {
        uint4 o0 = *(const uint4*)(rowp + h * 64);
        uint4 o1 = *(const uint4*)(rowp + h * 64 + 16);
        uint4 o2 = *(const uint4*)(rowp + h * 64 + 32);
        uint4 o3 = *(const uint4*)(rowp + h * 64 + 48);
        off16[0]=o0.x; off16[1]=o0.y; off16[2]=o0.z; off16[3]=o0.w;
        off16[4]=o1.x; off16[5]=o1.y; off16[6]=o1.z; off16[7]=o1.w;
        off16[8]=o2.x; off16[9]=o2.y; off16[10]=o2.z; off16[11]=o2.w;
        off16[12]=o3.x; off16[13]=o3.y; off16[14]=o3.z; off16[15]=o3.w;
    }

    float aw[16];
    {
        uint4 g0 = *(const uint4*)(rowp + 512 + h * 32);
        uint4 g1 = *(const uint4*)(rowp + 512 + h * 32 + 16);
        unsigned gu[8] = {g0.x,g0.y,g0.z,g0.w,g1.x,g1.y,g1.z,g1.w};
        float lg[16];
#pragma unroll
        for (int i = 0; i < 8; ++i) {
            f32x2 p = bfpair(gu[i]);
            lg[2*i] = p.x; lg[2*i+1] = p.y;
        }
        float mx = lg[0];
#pragma unroll
        for (int i = 1; i < 16; ++i) mx = fmaxf(mx, lg[i]);
        float ssum = 0.f;
#pragma unroll
        for (int i = 0; i < 16; ++i) { aw[i] = __expf(lg[i] - mx); ssum += aw[i]; }
        float inv = 1.f / ssum;
#pragma unroll
        for (int i = 0; i < 16; ++i) aw[i] *= inv;
    }

    f16x2 acc0 = {0, 0}, acc1 = {0, 0}, acc2 = {0, 0}, acc3 = {0, 0};

#pragma unroll
    for (int l = 0; l < 4; ++l) {
        const int W = LW[l], H = LH[l], Wp = PLW[l];
        const float xb = sRef[qrow][l * 2 + 0] * (float)W + 0.5f;   // pad-coord base
        const float yb = sRef[qrow][l * 2 + 1] * (float)H + 0.5f;
        const _Float16* vl = vproj + ((size_t)(b * PTOT + PLSTART[l])) * 256 + h * 32 + s * 8;
#pragma unroll
        for (int p = 0; p < 4; ++p) {
            const int t = l * 4 + p;
            f32x2 o2 = bfpair(off16[t]);
            float x = fminf(fmaxf(xb + o2.x, 0.f), (float)(W + 1));
            float y = fminf(fmaxf(yb + o2.y, 0.f), (float)(H + 1));
            float x0f = floorf(x), y0f = floorf(y);
            float lx = x - x0f, ly = y - y0f;
            int x0 = (int)x0f, y0 = (int)y0f;
            const _Float16* p00 = vl + (size_t)((y0 * Wp + x0) * 256);
            const _Float16* p10 = p00 + Wp * 256;
            float aww = aw[t];
            float wx0 = 1.f - lx;
            float wy0 = (1.f - ly) * aww, wy1 = ly * aww;
            float w00 = wx0 * wy0, w01 = lx * wy0;
            float w10 = wx0 * wy1, w11 = lx * wy1;
            _Float16 h00 = (_Float16)w00, h01 = (_Float16)w01;
            _Float16 h10 = (_Float16)w10, h11 = (_Float16)w11;

#define CORNERH(PTR, WH) { \
            const uint4 u = *(const uint4*)(PTR); \
            f16x2 wv2 = {WH, WH}; \
            acc0 += __builtin_bit_cast(f16x2, u.x) * wv2; \
            acc1 += __builtin_bit_cast(f16x2, u.y) * wv2; \
            acc2 += __builtin_bit_cast(f16x2, u.z) * wv2; \
            acc3 += __builtin_bit_cast(f16x2, u.w) * wv2; }
            CORNERH(p00, h00)
            CORNERH(p00 + 256, h01)
            CORNERH(p10, h10)
            CORNERH(p10 + 256, h11)
#undef CORNERH
        }
    }

    if (alive) {
        bf16 ob[8];
        ob[0] = __float2bfloat16((float)acc0[0]);
        ob[1] = __float2bfloat16((float)acc0[1]);
        ob[2] = __float2bfloat16((float)acc1[0]);
        ob[3] = __float2bfloat16((float)acc1[1]);
        ob[4] = __float2bfloat16((float)acc2[0]);
        ob[5] = __float2bfloat16((float)acc2[1]);
        ob[6] = __float2bfloat16((float)acc3[0]);
        ob[7] = __float2bfloat16((float)acc3[1]);
        *(uint4*)(msda_out + (size_t)q * 384 + h * 32 + s * 8) = *(const uint4*)ob;
    }
}

// ---------------------------------------------------------------------------
extern "C" void kernel_launch(void* const* d_in, const int* in_sizes, int n_in,
                              void* d_out, int out_size, void* d_ws, size_t ws_size,
                              hipStream_t stream) {
    const float* query = (const float*)d_in[0];
    const float* value = (const float*)d_in[1];
    const float* refp  = (const float*)d_in[2];
    const float* W_so  = (const float*)d_in[3];
    const float* b_so  = (const float*)d_in[4];
    const float* W_aw  = (const float*)d_in[5];
    const float* b_aw  = (const float*)d_in[6];
    const float* W_vp  = (const float*)d_in[7];
    const float* b_vp  = (const float*)d_in[8];
    const float* W_op  = (const float*)d_in[9];
    const float* b_op  = (const float*)d_in[10];
    float* out = (float*)d_out;

    // Workspace:
    //   offawl : bf16 MROWS*384 (34.1 MB) [off|awl]; msda aliased over rows
    //   vproj  : fp16 2*PTOT*256 (24.3 MB) zero-padded level layout
    //   weights: Wt_cat 384*256, Wt_vp/Wt_op 256*256 bf16, bcat 384 f32
    bf16*     d_offawl = (bf16*)d_ws;
    _Float16* d_vproj  = (_Float16*)(d_offawl + (size_t)MROWS * 384);
    bf16*     d_wtcat  = (bf16*)(d_vproj + (size_t)2 * PTOT * 256);
    bf16*     d_wtvp   = d_wtcat + 384 * 256;
    bf16*     d_wtop   = d_wtvp + 256 * 256;
    float*    d_bcat   = (float*)(d_wtop + 256 * 256);

    prep_weights<<<384, 256, 0, stream>>>(W_vp, W_so, W_aw, W_op, b_so, b_aw,
                                          d_wtvp, d_wtcat, d_wtop, d_bcat);
    hipMemsetAsync(d_vproj, 0, (size_t)2 * PTOT * 256 * sizeof(_Float16), stream);

    gemm_producer<<<GX * 5, 256, 0, stream>>>(
        query, value, d_wtcat, d_wtvp, d_bcat, b_vp, d_offawl, d_vproj);

    msda_sample7<<<(MROWS + 7) / 8, 256, 0, stream>>>(
        d_vproj, d_offawl, refp, d_offawl);

    gemm_out<<<GX * 2, 256, 0, stream>>>(d_offawl, d_wtop, b_op, query, out);
}

// Round 8
// 170.201 us; speedup vs baseline: 4.0689x; 1.0027x over previous
//
#include <hip/hip_runtime.h>
#include <hip/hip_bf16.h>
#include <math.h>

typedef __hip_bfloat16 bf16;
using f32x4  = __attribute__((ext_vector_type(4))) float;
using f32x2  = __attribute__((ext_vector_type(2))) float;
using bf16x8 = __attribute__((ext_vector_type(8))) short;
using f16x2  = __attribute__((ext_vector_type(2))) _Float16;

constexpr int BS = 2, NQ = 22223, MROWS = 44446;
constexpr int LH[4] = {100, 50, 25, 13};
constexpr int LW[4] = {167, 84, 42, 21};
constexpr int LSTART[4] = {0, 16700, 20900, 21950};
// Padded levels: +1 left/top, +2 right/bottom (Wp=W+3, Hp=H+3)
constexpr int PLW[4] = {170, 87, 45, 24};
constexpr int PLSTART[4] = {0, 17510, 22121, 23381};
constexpr int PTOT = 23765;

constexpr int BM = 128, BK = 32;
constexpr int LDT = 40;               // LDS row stride (bf16): 80B
constexpr int GX = (MROWS + BM - 1) / BM;   // 348

// ---------------------------------------------------------------------------
__global__ __launch_bounds__(256) void prep_weights(
    const float* __restrict__ W_vp, const float* __restrict__ W_so,
    const float* __restrict__ W_aw, const float* __restrict__ W_op,
    const float* __restrict__ b_so, const float* __restrict__ b_aw,
    bf16* __restrict__ Wt_vp, bf16* __restrict__ Wt_cat,
    bf16* __restrict__ Wt_op, float* __restrict__ bcat)
{
    int i = blockIdx.x * 256 + threadIdx.x;
    if (i < 256 * 256) {
        int n = i >> 8, k = i & 255;
        Wt_vp[i] = __float2bfloat16(W_vp[k * 256 + n]);
        Wt_op[i] = __float2bfloat16(W_op[k * 256 + n]);
    }
    if (i < 384 * 256) {
        int n = i >> 8, k = i & 255;
        float v = (n < 256) ? W_so[k * 256 + n] : W_aw[k * 128 + (n - 256)];
        Wt_cat[i] = __float2bfloat16(v);
    }
    if (i < 384) bcat[i] = (i < 256) ? b_so[i] : b_aw[i - 256];
}

// Map flat value-row -> padded vproj pixel index
__device__ inline int pad_row_idx(int r) {
    int b = 0, pix = r;
    if (pix >= NQ) { b = 1; pix -= NQ; }
    int base;
    if (pix < LSTART[1])      { int rel = pix;             int y = rel / 167; int x = rel - y * 167; base = PLSTART[0] + (y + 1) * 170 + (x + 1); }
    else if (pix < LSTART[2]) { int rel = pix - LSTART[1]; int y = rel / 84;  int x = rel - y * 84;  base = PLSTART[1] + (y + 1) * 87  + (x + 1); }
    else if (pix < LSTART[3]) { int rel = pix - LSTART[2]; int y = rel / 42;  int x = rel - y * 42;  base = PLSTART[2] + (y + 1) * 45  + (x + 1); }
    else                      { int rel = pix - LSTART[3]; int y = rel / 21;  int x = rel - y * 21;  base = PLSTART[3] + (y + 1) * 24  + (x + 1); }
    return b * PTOT + base;
}

// ---------------------------------------------------------------------------
// Shared MFMA tile core: acc[4][4] (64x64 per wave) over K=256, BK=32.
// ---------------------------------------------------------------------------
template<bool A_BF16>
__device__ __forceinline__ void mfma_core(
    const void* __restrict__ Av, int lda, const bf16* __restrict__ Wt,
    int row0, int bn0, int M, bf16* As, bf16* Bs, f32x4 (&acc)[4][4])
{
    const int tid = threadIdx.x;
    const int lane = tid & 63;
    const int wv = tid >> 6;
    const int wm = (wv >> 1) * 64, wn = (wv & 1) * 64;
    const int l15 = lane & 15, l4 = lane >> 4;

#pragma unroll
    for (int m = 0; m < 4; ++m)
#pragma unroll
        for (int n = 0; n < 4; ++n) { acc[m][n][0]=0.f; acc[m][n][1]=0.f; acc[m][n][2]=0.f; acc[m][n][3]=0.f; }

    for (int k0 = 0; k0 < 256; k0 += BK) {
        __syncthreads();
#pragma unroll
        for (int t = 0; t < 2; ++t) {
            int idx = tid + t * 256;
            int r = idx >> 2, s = idx & 3;
            {
                int grow = row0 + r; if (grow >= M) grow = M - 1;
                bf16 tmp[8];
                if constexpr (A_BF16) {
                    const bf16* ap = (const bf16*)Av + (size_t)grow * lda + (k0 + s * 8);
                    *(uint4*)tmp = *(const uint4*)ap;
                } else {
                    const float* ap = (const float*)Av + (size_t)grow * lda + (k0 + s * 8);
                    f32x4 v0 = *(const f32x4*)ap;
                    f32x4 v1 = *(const f32x4*)(ap + 4);
#pragma unroll
                    for (int j = 0; j < 4; ++j) tmp[j] = __float2bfloat16(v0[j]);
#pragma unroll
                    for (int j = 0; j < 4; ++j) tmp[4 + j] = __float2bfloat16(v1[j]);
                }
                *(uint4*)&As[r * LDT + s * 8] = *(const uint4*)tmp;
            }
            *(uint4*)&Bs[r * LDT + s * 8] =
                *(const uint4*)(Wt + (size_t)(bn0 + r) * 256 + (k0 + s * 8));
        }
        __syncthreads();

        bf16x8 af[4], bfr[4];
#pragma unroll
        for (int m = 0; m < 4; ++m)
            af[m] = *(const bf16x8*)&As[(wm + m * 16 + l15) * LDT + l4 * 8];
#pragma unroll
        for (int n = 0; n < 4; ++n)
            bfr[n] = *(const bf16x8*)&Bs[(wn + n * 16 + l15) * LDT + l4 * 8];
#pragma unroll
        for (int m = 0; m < 4; ++m)
#pragma unroll
            for (int n = 0; n < 4; ++n)
                acc[m][n] = __builtin_amdgcn_mfma_f32_16x16x32_bf16(af[m], bfr[n], acc[m][n], 0, 0, 0);
    }
}

// ---------------------------------------------------------------------------
// Fused producer GEMM: 5 N-slices per row-panel (3 offawl bf16 + 2 vproj fp16
// padded-scatter), slice-fastest linearization + bijective XCD swizzle.
// ---------------------------------------------------------------------------
__global__ __launch_bounds__(256) void gemm_producer(
    const float* __restrict__ query, const float* __restrict__ value,
    const bf16* __restrict__ Wt_cat, const bf16* __restrict__ Wt_vp,
    const float* __restrict__ bcat, const float* __restrict__ bvp,
    bf16* __restrict__ offawl, _Float16* __restrict__ vproj)
{
    __shared__ bf16 As[BM * LDT];
    __shared__ bf16 Bs[BM * LDT];

    constexpr int NWG = GX * 5;                 // 1740
    constexpr int QXW = NWG / 8, RXW = NWG % 8; // 217, 4
    int orig = blockIdx.x;
    int xcd = orig & 7, seq = orig >> 3;
    int swz = (xcd < RXW ? xcd * (QXW + 1) : RXW * (QXW + 1) + (xcd - RXW) * QXW) + seq;
    int slice = swz % 5;
    int row0 = (swz / 5) * BM;

    const bool isOff = slice < 3;
    const void* A = isOff ? (const void*)query : (const void*)value;
    const bf16* Wt = isOff ? Wt_cat : Wt_vp;
    const float* bias = isOff ? bcat : bvp;
    int bn0 = isOff ? slice * 128 : (slice - 3) * 128;

    f32x4 acc[4][4];
    mfma_core<false>(A, 256, Wt, row0, bn0, MROWS, As, Bs, acc);

    const int lane = threadIdx.x & 63;
    const int wv = threadIdx.x >> 6;
    const int wm = (wv >> 1) * 64, wn = (wv & 1) * 64;
    const int l15 = lane & 15, l4 = lane >> 4;

    if (isOff) {
#pragma unroll
        for (int m = 0; m < 4; ++m)
#pragma unroll
            for (int j = 0; j < 4; ++j) {
                int r = row0 + wm + m * 16 + l4 * 4 + j;
                if (r < MROWS) {
                    bf16* orow = offawl + (size_t)r * 384;
#pragma unroll
                    for (int n = 0; n < 4; ++n) {
                        int fcol = bn0 + wn + n * 16 + l15;
                        orow[fcol] = __float2bfloat16(acc[m][n][j] + bias[fcol]);
                    }
                }
            }
    } else {
#pragma unroll
        for (int m = 0; m < 4; ++m)
#pragma unroll
            for (int j = 0; j < 4; ++j) {
                int r = row0 + wm + m * 16 + l4 * 4 + j;
                if (r < MROWS) {
                    _Float16* orow = vproj + (size_t)pad_row_idx(r) * 256;
#pragma unroll
                    for (int n = 0; n < 4; ++n) {
                        int fcol = bn0 + wn + n * 16 + l15;
                        orow[fcol] = (_Float16)(acc[m][n][j] + bias[fcol]);
                    }
                }
            }
    }
}

// ---------------------------------------------------------------------------
// Output GEMM: out = msda(bf16, ld 384) @ W_op^T + b_op + query.
// ---------------------------------------------------------------------------
__global__ __launch_bounds__(256) void gemm_out(
    const bf16* __restrict__ msda, const bf16* __restrict__ Wt_op,
    const float* __restrict__ b_op, const float* __restrict__ query,
    float* __restrict__ out)
{
    __shared__ bf16 As[BM * LDT];
    __shared__ bf16 Bs[BM * LDT];

    constexpr int NWG = GX * 2;  // 696
    int orig = blockIdx.x;
    int swz = (orig & 7) * (NWG / 8) + (orig >> 3);
    int bn0 = (swz & 1) * 128;
    int row0 = (swz >> 1) * BM;

    f32x4 acc[4][4];
    mfma_core<true>(msda, 384, Wt_op, row0, bn0, MROWS, As, Bs, acc);

    const int lane = threadIdx.x & 63;
    const int wv = threadIdx.x >> 6;
    const int wm = (wv >> 1) * 64, wn = (wv & 1) * 64;
    const int l15 = lane & 15, l4 = lane >> 4;

#pragma unroll
    for (int m = 0; m < 4; ++m)
#pragma unroll
        for (int j = 0; j < 4; ++j) {
            int r = row0 + wm + m * 16 + l4 * 4 + j;
            if (r < MROWS) {
#pragma unroll
                for (int n = 0; n < 4; ++n) {
                    int fcol = bn0 + wn + n * 16 + l15;
                    out[(size_t)r * 256 + fcol] =
                        acc[m][n][j] + b_op[fcol] + query[(size_t)r * 256 + fcol];
                }
            }
        }
}

// ---------------------------------------------------------------------------
// MSDA sampling v8 = v7 + per-level batched gathers (16 uint4 in flight) and
// __launch_bounds__(256,4) so the allocator keeps them in registers.
// Memory-level parallelism per wave: 4 -> 16 outstanding loads.
// ---------------------------------------------------------------------------
__device__ inline f32x2 bfpair(unsigned u) {
    f32x2 r;
    r.x = __uint_as_float(u << 16);
    r.y = __uint_as_float(u & 0xffff0000u);
    return r;
}

__global__ __launch_bounds__(256, 4) void msda_sample8(
    const _Float16* __restrict__ vproj,  // padded layout [2*PTOT][256] fp16
    const bf16* __restrict__ offawl,     // [MROWS][384] bf16
    const float* __restrict__ refp,
    bf16* __restrict__ msda_out)         // aliases offawl rows (stride 384)
{
    __shared__ uint2 sOA[8][128];        // 8 rows x 1024B (payload 768B)
    __shared__ float sRef[8][8];

    // bijective XCD swizzle (kept: harmless, and helps when locality exists)
    constexpr int NBLK = (MROWS + 7) / 8;        // 5556
    constexpr int QX = NBLK / 8, RX = NBLK % 8;  // 694, 4
    const int orig = blockIdx.x;
    const int xcd = orig & 7, seq = orig >> 3;
    const int blk = (xcd < RX ? xcd * (QX + 1) : RX * (QX + 1) + (xcd - RX) * QX) + seq;
    const int q0 = blk * 8;

    const int tid = threadIdx.x;

#pragma unroll
    for (int k = 0; k < 4; ++k) {
        int idx = tid + k * 256;
        int row = idx >> 7, e = idx & 127;
        if (e < 96) {
            int grow = min(q0 + row, MROWS - 1);
            sOA[row][e] = *((const uint2*)(offawl + (size_t)grow * 384) + e);
        }
    }
    if (tid < 64) {
        int row = tid >> 3, er = tid & 7;
        int grow = min(q0 + row, MROWS - 1);
        sRef[row][er] = refp[(size_t)grow * 8 + er];
    }
    __syncthreads();

    const int w = tid >> 6;
    const int lane = tid & 63;
    const int qs = lane >> 5;
    const int h = (lane >> 2) & 7;
    const int s = lane & 3;
    const int qrow = w * 2 + qs;
    int q = q0 + qrow;
    const bool alive = q < MROWS;
    if (!alive) q = MROWS - 1;
    const int b = (q >= NQ) ? 1 : 0;

    const char* rowp = (const char*)&sOA[qrow][0];
    unsigned off16[16];
    {
        uint4 o0 = *(const uint4*)(rowp + h * 64);
        uint4 o1 = *(const uint4*)(rowp + h * 64 + 16);
        uint4 o2 = *(const uint4*)(rowp + h * 64 + 32);
        uint4 o3 = *(const uint4*)(rowp + h * 64 + 48);
        off16[0]=o0.x; off16[1]=o0.y; off16[2]=o0.z; off16[3]=o0.w;
        off16[4]=o1.x; off16[5]=o1.y; off16[6]=o1.z; off16[7]=o1.w;
        off16[8]=o2.x; off16[9]=o2.y; off16[10]=o2.z; off16[11]=o2.w;
        off16[12]=o3.x; off16[13]=o3.y; off16[14]=o3.z; off16[15]=o3.w;
    }

    float aw[16];
    {
        uint4 g0 = *(const uint4*)(rowp + 512 + h * 32);
        uint4 g1 = *(const uint4*)(rowp + 512 + h * 32 + 16);
        unsigned gu[8] = {g0.x,g0.y,g0.z,g0.w,g1.x,g1.y,g1.z,g1.w};
        float lg[16];
#pragma unroll
        for (int i = 0; i < 8; ++i) {
            f32x2 p = bfpair(gu[i]);
            lg[2*i] = p.x; lg[2*i+1] = p.y;
        }
        float mx = lg[0];
#pragma unroll
        for (int i = 1; i < 16; ++i) mx = fmaxf(mx, lg[i]);
        float ssum = 0.f;
#pragma unroll
        for (int i = 0; i < 16; ++i) { aw[i] = __expf(lg[i] - mx); ssum += aw[i]; }
        float inv = 1.f / ssum;
#pragma unroll
        for (int i = 0; i < 16; ++i) aw[i] *= inv;
    }

    f16x2 acc0 = {0, 0}, acc1 = {0, 0}, acc2 = {0, 0}, acc3 = {0, 0};

#pragma unroll
    for (int l = 0; l < 4; ++l) {
        const int W = LW[l], H = LH[l], Wp = PLW[l];
        const float xb = sRef[qrow][l * 2 + 0] * (float)W + 0.5f;   // pad-coord base
        const float yb = sRef[qrow][l * 2 + 1] * (float)H + 0.5f;
        const _Float16* vl = vproj + ((size_t)(b * PTOT + PLSTART[l])) * 256 + h * 32 + s * 8;

        // Phase 1: addresses + packed fp16 weights for all 4 taps of this level
        const _Float16* p00[4];
        f16x2 hw[4][4];
#pragma unroll
        for (int p = 0; p < 4; ++p) {
            const int t = l * 4 + p;
            f32x2 o2 = bfpair(off16[t]);
            float x = fminf(fmaxf(xb + o2.x, 0.f), (float)(W + 1));
            float y = fminf(fmaxf(yb + o2.y, 0.f), (float)(H + 1));
            float x0f = floorf(x), y0f = floorf(y);
            float lx = x - x0f, ly = y - y0f;
            int x0 = (int)x0f, y0 = (int)y0f;
            p00[p] = vl + (size_t)((y0 * Wp + x0) * 256);
            float aww = aw[t];
            float wx0 = 1.f - lx;
            float wy0 = (1.f - ly) * aww, wy1 = ly * aww;
            _Float16 h00 = (_Float16)(wx0 * wy0), h01 = (_Float16)(lx * wy0);
            _Float16 h10 = (_Float16)(wx0 * wy1), h11 = (_Float16)(lx * wy1);
            hw[p][0] = f16x2{h00, h00}; hw[p][1] = f16x2{h01, h01};
            hw[p][2] = f16x2{h10, h10}; hw[p][3] = f16x2{h11, h11};
        }

        // Phase 2: issue all 16 gathers (stay in flight together)
        uint4 c[4][4];
#pragma unroll
        for (int p = 0; p < 4; ++p) {
            c[p][0] = *(const uint4*)(p00[p]);
            c[p][1] = *(const uint4*)(p00[p] + 256);
            c[p][2] = *(const uint4*)(p00[p] + Wp * 256);
            c[p][3] = *(const uint4*)(p00[p] + Wp * 256 + 256);
        }

        // Phase 3: packed fp16 FMAs
#pragma unroll
        for (int p = 0; p < 4; ++p)
#pragma unroll
            for (int cc = 0; cc < 4; ++cc) {
                acc0 += __builtin_bit_cast(f16x2, c[p][cc].x) * hw[p][cc];
                acc1 += __builtin_bit_cast(f16x2, c[p][cc].y) * hw[p][cc];
                acc2 += __builtin_bit_cast(f16x2, c[p][cc].z) * hw[p][cc];
                acc3 += __builtin_bit_cast(f16x2, c[p][cc].w) * hw[p][cc];
            }
    }

    if (alive) {
        bf16 ob[8];
        ob[0] = __float2bfloat16((float)acc0[0]);
        ob[1] = __float2bfloat16((float)acc0[1]);
        ob[2] = __float2bfloat16((float)acc1[0]);
        ob[3] = __float2bfloat16((float)acc1[1]);
        ob[4] = __float2bfloat16((float)acc2[0]);
        ob[5] = __float2bfloat16((float)acc2[1]);
        ob[6] = __float2bfloat16((float)acc3[0]);
        ob[7] = __float2bfloat16((float)acc3[1]);
        *(uint4*)(msda_out + (size_t)q * 384 + h * 32 + s * 8) = *(const uint4*)ob;
    }
}

// ---------------------------------------------------------------------------
extern "C" void kernel_launch(void* const* d_in, const int* in_sizes, int n_in,
                              void* d_out, int out_size, void* d_ws, size_t ws_size,
                              hipStream_t stream) {
    const float* query = (const float*)d_in[0];
    const float* value = (const float*)d_in[1];
    const float* refp  = (const float*)d_in[2];
    const float* W_so  = (const float*)d_in[3];
    const float* b_so  = (const float*)d_in[4];
    const float* W_aw  = (const float*)d_in[5];
    const float* b_aw  = (const float*)d_in[6];
    const float* W_vp  = (const float*)d_in[7];
    const float* b_vp  = (const float*)d_in[8];
    const float* W_op  = (const float*)d_in[9];
    const float* b_op  = (const float*)d_in[10];
    float* out = (float*)d_out;

    // Workspace:
    //   offawl : bf16 MROWS*384 (34.1 MB) [off|awl]; msda aliased over rows
    //   vproj  : fp16 2*PTOT*256 (24.3 MB) zero-padded level layout
    //   weights: Wt_cat 384*256, Wt_vp/Wt_op 256*256 bf16, bcat 384 f32
    bf16*     d_offawl = (bf16*)d_ws;
    _Float16* d_vproj  = (_Float16*)(d_offawl + (size_t)MROWS * 384);
    bf16*     d_wtcat  = (bf16*)(d_vproj + (size_t)2 * PTOT * 256);
    bf16*     d_wtvp   = d_wtcat + 384 * 256;
    bf16*     d_wtop   = d_wtvp + 256 * 256;
    float*    d_bcat   = (float*)(d_wtop + 256 * 256);

    prep_weights<<<384, 256, 0, stream>>>(W_vp, W_so, W_aw, W_op, b_so, b_aw,
                                          d_wtvp, d_wtcat, d_wtop, d_bcat);
    hipMemsetAsync(d_vproj, 0, (size_t)2 * PTOT * 256 * sizeof(_Float16), stream);

    gemm_producer<<<GX * 5, 256, 0, stream>>>(
        query, value, d_wtcat, d_wtvp, d_bcat, b_vp, d_offawl, d_vproj);

    msda_sample8<<<(MROWS + 7) / 8, 256, 0, stream>>>(
        d_vproj, d_offawl, refp, d_offawl);

    gemm_out<<<GX * 2, 256, 0, stream>>>(d_offawl, d_wtop, b_op, query, out);
}

// Round 10
// 164.329 us; speedup vs baseline: 4.2143x; 1.0357x over previous
//
#include <hip/hip_runtime.h>
#include <hip/hip_bf16.h>
#include <math.h>

typedef __hip_bfloat16 bf16;
using f32x4  = __attribute__((ext_vector_type(4))) float;
using f32x2  = __attribute__((ext_vector_type(2))) float;
using bf16x8 = __attribute__((ext_vector_type(8))) short;
using f16x2  = __attribute__((ext_vector_type(2))) _Float16;

constexpr int BS = 2, NQ = 22223, MROWS = 44446;
constexpr int LH[4] = {100, 50, 25, 13};
constexpr int LW[4] = {167, 84, 42, 21};
constexpr int LSTART[4] = {0, 16700, 20900, 21950};
// Padded levels: +1 left/top, +2 right/bottom (Wp=W+3, Hp=H+3)
constexpr int PLW[4] = {170, 87, 45, 24};
constexpr int PLSTART[4] = {0, 17510, 22121, 23381};
constexpr int PTOT = 23765;

constexpr int BM = 128, BK = 32;
constexpr int LDT = 40;               // LDS row stride (bf16): 80B
constexpr int GX = (MROWS + BM - 1) / BM;   // 348

// ---------------------------------------------------------------------------
__global__ __launch_bounds__(256) void prep_weights(
    const float* __restrict__ W_vp, const float* __restrict__ W_so,
    const float* __restrict__ W_aw, const float* __restrict__ W_op,
    const float* __restrict__ b_so, const float* __restrict__ b_aw,
    bf16* __restrict__ Wt_vp, bf16* __restrict__ Wt_cat,
    bf16* __restrict__ Wt_op, float* __restrict__ bcat)
{
    int i = blockIdx.x * 256 + threadIdx.x;
    if (i < 256 * 256) {
        int n = i >> 8, k = i & 255;
        Wt_vp[i] = __float2bfloat16(W_vp[k * 256 + n]);
        Wt_op[i] = __float2bfloat16(W_op[k * 256 + n]);
    }
    if (i < 384 * 256) {
        int n = i >> 8, k = i & 255;
        float v = (n < 256) ? W_so[k * 256 + n] : W_aw[k * 128 + (n - 256)];
        Wt_cat[i] = __float2bfloat16(v);
    }
    if (i < 384) bcat[i] = (i < 256) ? b_so[i] : b_aw[i - 256];
}

// Map batch-local value pixel -> level-local padded pixel index (+1,+1 offset)
__device__ inline int pad_base_idx(int pix) {
    if (pix < LSTART[1])      { int y = pix / 167;                  int x = pix - y * 167;                return PLSTART[0] + (y + 1) * 170 + (x + 1); }
    else if (pix < LSTART[2]) { int rel = pix - LSTART[1]; int y = rel / 84; int x = rel - y * 84;        return PLSTART[1] + (y + 1) * 87  + (x + 1); }
    else if (pix < LSTART[3]) { int rel = pix - LSTART[2]; int y = rel / 42; int x = rel - y * 42;        return PLSTART[2] + (y + 1) * 45  + (x + 1); }
    else                      { int rel = pix - LSTART[3]; int y = rel / 21; int x = rel - y * 21;        return PLSTART[3] + (y + 1) * 24  + (x + 1); }
}

// ---------------------------------------------------------------------------
// Shared MFMA tile core: acc[4][4] (64x64 per wave) over K=256, BK=32.
// ---------------------------------------------------------------------------
template<bool A_BF16>
__device__ __forceinline__ void mfma_core(
    const void* __restrict__ Av, int lda, const bf16* __restrict__ Wt,
    int row0, int bn0, int M, bf16* As, bf16* Bs, f32x4 (&acc)[4][4])
{
    const int tid = threadIdx.x;
    const int lane = tid & 63;
    const int wv = tid >> 6;
    const int wm = (wv >> 1) * 64, wn = (wv & 1) * 64;
    const int l15 = lane & 15, l4 = lane >> 4;

#pragma unroll
    for (int m = 0; m < 4; ++m)
#pragma unroll
        for (int n = 0; n < 4; ++n) { acc[m][n][0]=0.f; acc[m][n][1]=0.f; acc[m][n][2]=0.f; acc[m][n][3]=0.f; }

    for (int k0 = 0; k0 < 256; k0 += BK) {
        __syncthreads();
#pragma unroll
        for (int t = 0; t < 2; ++t) {
            int idx = tid + t * 256;
            int r = idx >> 2, s = idx & 3;
            {
                int grow = row0 + r; if (grow >= M) grow = M - 1;
                bf16 tmp[8];
                if constexpr (A_BF16) {
                    const bf16* ap = (const bf16*)Av + (size_t)grow * lda + (k0 + s * 8);
                    *(uint4*)tmp = *(const uint4*)ap;
                } else {
                    const float* ap = (const float*)Av + (size_t)grow * lda + (k0 + s * 8);
                    f32x4 v0 = *(const f32x4*)ap;
                    f32x4 v1 = *(const f32x4*)(ap + 4);
#pragma unroll
                    for (int j = 0; j < 4; ++j) tmp[j] = __float2bfloat16(v0[j]);
#pragma unroll
                    for (int j = 0; j < 4; ++j) tmp[4 + j] = __float2bfloat16(v1[j]);
                }
                *(uint4*)&As[r * LDT + s * 8] = *(const uint4*)tmp;
            }
            *(uint4*)&Bs[r * LDT + s * 8] =
                *(const uint4*)(Wt + (size_t)(bn0 + r) * 256 + (k0 + s * 8));
        }
        __syncthreads();

        bf16x8 af[4], bfr[4];
#pragma unroll
        for (int m = 0; m < 4; ++m)
            af[m] = *(const bf16x8*)&As[(wm + m * 16 + l15) * LDT + l4 * 8];
#pragma unroll
        for (int n = 0; n < 4; ++n)
            bfr[n] = *(const bf16x8*)&Bs[(wn + n * 16 + l15) * LDT + l4 * 8];
#pragma unroll
        for (int m = 0; m < 4; ++m)
#pragma unroll
            for (int n = 0; n < 4; ++n)
                acc[m][n] = __builtin_amdgcn_mfma_f32_16x16x32_bf16(af[m], bfr[n], acc[m][n], 0, 0, 0);
    }
}

// ---------------------------------------------------------------------------
// Fused producer GEMM: 5 N-slices per row-panel (3 offawl bf16 + 2 vproj fp16
// head-major scatter), slice-fastest linearization + bijective XCD swizzle.
// vproj layout: [head][batch][padded_pixel][32ch] fp16 (pixel stride 64B).
// ---------------------------------------------------------------------------
__global__ __launch_bounds__(256) void gemm_producer(
    const float* __restrict__ query, const float* __restrict__ value,
    const bf16* __restrict__ Wt_cat, const bf16* __restrict__ Wt_vp,
    const float* __restrict__ bcat, const float* __restrict__ bvp,
    bf16* __restrict__ offawl, _Float16* __restrict__ vproj)
{
    __shared__ bf16 As[BM * LDT];
    __shared__ bf16 Bs[BM * LDT];

    constexpr int NWG = GX * 5;                 // 1740
    constexpr int QXW = NWG / 8, RXW = NWG % 8; // 217, 4
    int orig = blockIdx.x;
    int xcd = orig & 7, seq = orig >> 3;
    int swz = (xcd < RXW ? xcd * (QXW + 1) : RXW * (QXW + 1) + (xcd - RXW) * QXW) + seq;
    int slice = swz % 5;
    int row0 = (swz / 5) * BM;

    const bool isOff = slice < 3;
    const void* A = isOff ? (const void*)query : (const void*)value;
    const bf16* Wt = isOff ? Wt_cat : Wt_vp;
    const float* bias = isOff ? bcat : bvp;
    int bn0 = isOff ? slice * 128 : (slice - 3) * 128;

    f32x4 acc[4][4];
    mfma_core<false>(A, 256, Wt, row0, bn0, MROWS, As, Bs, acc);

    const int lane = threadIdx.x & 63;
    const int wv = threadIdx.x >> 6;
    const int wm = (wv >> 1) * 64, wn = (wv & 1) * 64;
    const int l15 = lane & 15, l4 = lane >> 4;

    if (isOff) {
#pragma unroll
        for (int m = 0; m < 4; ++m)
#pragma unroll
            for (int j = 0; j < 4; ++j) {
                int r = row0 + wm + m * 16 + l4 * 4 + j;
                if (r < MROWS) {
                    bf16* orow = offawl + (size_t)r * 384;
#pragma unroll
                    for (int n = 0; n < 4; ++n) {
                        int fcol = bn0 + wn + n * 16 + l15;
                        orow[fcol] = __float2bfloat16(acc[m][n][j] + bias[fcol]);
                    }
                }
            }
    } else {
#pragma unroll
        for (int m = 0; m < 4; ++m)
#pragma unroll
            for (int j = 0; j < 4; ++j) {
                int r = row0 + wm + m * 16 + l4 * 4 + j;
                if (r < MROWS) {
                    int bb = (r >= NQ) ? 1 : 0;
                    int pb = pad_base_idx(r - bb * NQ);
#pragma unroll
                    for (int n = 0; n < 4; ++n) {
                        int fcol = bn0 + wn + n * 16 + l15;
                        int hh = fcol >> 5, cc = fcol & 31;
                        vproj[((size_t)(hh * 2 + bb) * PTOT + pb) * 32 + cc] =
                            (_Float16)(acc[m][n][j] + bias[fcol]);
                    }
                }
            }
    }
}

// ---------------------------------------------------------------------------
// Output GEMM: out = msda(bf16, ld 384) @ W_op^T + b_op + query.
// ---------------------------------------------------------------------------
__global__ __launch_bounds__(256) void gemm_out(
    const bf16* __restrict__ msda, const bf16* __restrict__ Wt_op,
    const float* __restrict__ b_op, const float* __restrict__ query,
    float* __restrict__ out)
{
    __shared__ bf16 As[BM * LDT];
    __shared__ bf16 Bs[BM * LDT];

    constexpr int NWG = GX * 2;  // 696
    int orig = blockIdx.x;
    int swz = (orig & 7) * (NWG / 8) + (orig >> 3);
    int bn0 = (swz & 1) * 128;
    int row0 = (swz >> 1) * BM;

    f32x4 acc[4][4];
    mfma_core<true>(msda, 384, Wt_op, row0, bn0, MROWS, As, Bs, acc);

    const int lane = threadIdx.x & 63;
    const int wv = threadIdx.x >> 6;
    const int wm = (wv >> 1) * 64, wn = (wv & 1) * 64;
    const int l15 = lane & 15, l4 = lane >> 4;

#pragma unroll
    for (int m = 0; m < 4; ++m)
#pragma unroll
        for (int j = 0; j < 4; ++j) {
            int r = row0 + wm + m * 16 + l4 * 4 + j;
            if (r < MROWS) {
#pragma unroll
                for (int n = 0; n < 4; ++n) {
                    int fcol = bn0 + wn + n * 16 + l15;
                    out[(size_t)r * 256 + fcol] =
                        acc[m][n][j] + b_op[fcol] + query[(size_t)r * 256 + fcol];
                }
            }
        }
}

// ---------------------------------------------------------------------------
// MSDA sampling v10 = R8 structure + head-major 64B-pixel vproj (x-adjacent
// corners share one 128B line) + amdgpu_waves_per_eu(2,4) to give the
// scheduler a 128-VGPR budget so the per-level 16-load batch stays in flight.
// 2 queries per wave, 8 per block; lane = qs*32 + h*4 + s owns 8 channels.
// ---------------------------------------------------------------------------
__device__ inline f32x2 bfpair(unsigned u) {
    f32x2 r;
    r.x = __uint_as_float(u << 16);
    r.y = __uint_as_float(u & 0xffff0000u);
    return r;
}

__global__ __launch_bounds__(256)
__attribute__((amdgpu_waves_per_eu(2, 4)))
void msda_sample10(
    const _Float16* __restrict__ vproj,  // [head][batch][ppix][32] fp16
    const bf16* __restrict__ offawl,     // [MROWS][384] bf16
    const float* __restrict__ refp,
    bf16* __restrict__ msda_out)         // aliases offawl rows (stride 384)
{
    __shared__ uint2 sOA[8][128];        // 8 rows x 1024B (payload 768B)
    __shared__ float sRef[8][8];

    // bijective XCD swizzle
    constexpr int NBLK = (MROWS + 7) / 8;        // 5556
    constexpr int QX = NBLK / 8, RX = NBLK % 8;  // 694, 4
    const int orig = blockIdx.x;
    const int xcd = orig & 7, seq = orig >> 3;
    const int blk = (xcd < RX ? xcd * (QX + 1) : RX * (QX + 1) + (xcd - RX) * QX) + seq;
    const int q0 = blk * 8;

    const int tid = threadIdx.x;

#pragma unroll
    for (int k = 0; k < 4; ++k) {
        int idx = tid + k * 256;
        int row = idx >> 7, e = idx & 127;
        if (e < 96) {
            int grow = min(q0 + row, MROWS - 1);
            sOA[row][e] = *((const uint2*)(offawl + (size_t)grow * 384) + e);
        }
    }
    if (tid < 64) {
        int row = tid >> 3, er = tid & 7;
        int grow = min(q0 + row, MROWS - 1);
        sRef[row][er] = refp[(size_t)grow * 8 + er];
    }
    __syncthreads();

    const int w = tid >> 6;
    const int lane = tid & 63;
    const int qs = lane >> 5;
    const int h = (lane >> 2) & 7;
    const int s = lane & 3;
    const int qrow = w * 2 + qs;
    int q = q0 + qrow;
    const bool alive = q < MROWS;
    if (!alive) q = MROWS - 1;
    const int b = (q >= NQ) ? 1 : 0;

    const char* rowp = (const char*)&sOA[qrow][0];
    unsigned off16[16];
    {
        uint4 o0 = *(const uint4*)(rowp + h * 64);
        uint4 o1 = *(const uint4*)(rowp + h * 64 + 16);
        uint4 o2 = *(const uint4*)(rowp + h * 64 + 32);
        uint4 o3 = *(const uint4*)(rowp + h * 64 + 48);
        off16[0]=o0.x; off16[1]=o0.y; off16[2]=o0.z; off16[3]=o0.w;
        off16[4]=o1.x; off16[5]=o1.y; off16[6]=o1.z; off16[7]=o1.w;
        off16[8]=o2.x; off16[9]=o2.y; off16[10]=o2.z; off16[11]=o2.w;
        off16[12]=o3.x; off16[13]=o3.y; off16[14]=o3.z; off16[15]=o3.w;
    }

    float aw[16];
    {
        uint4 g0 = *(const uint4*)(rowp + 512 + h * 32);
        uint4 g1 = *(const uint4*)(rowp + 512 + h * 32 + 16);
        unsigned gu[8] = {g0.x,g0.y,g0.z,g0.w,g1.x,g1.y,g1.z,g1.w};
        float lg[16];
#pragma unroll
        for (int i = 0; i < 8; ++i) {
            f32x2 p = bfpair(gu[i]);
            lg[2*i] = p.x; lg[2*i+1] = p.y;
        }
        float mx = lg[0];
#pragma unroll
        for (int i = 1; i < 16; ++i) mx = fmaxf(mx, lg[i]);
        float ssum = 0.f;
#pragma unroll
        for (int i = 0; i < 16; ++i) { aw[i] = __expf(lg[i] - mx); ssum += aw[i]; }
        float inv = 1.f / ssum;
#pragma unroll
        for (int i = 0; i < 16; ++i) aw[i] *= inv;
    }

    f16x2 acc0 = {0, 0}, acc1 = {0, 0}, acc2 = {0, 0}, acc3 = {0, 0};

#pragma unroll
    for (int l = 0; l < 4; ++l) {
        const int W = LW[l], H = LH[l], Wp = PLW[l];
        const float xb = sRef[qrow][l * 2 + 0] * (float)W + 0.5f;   // pad-coord base
        const float yb = sRef[qrow][l * 2 + 1] * (float)H + 0.5f;
        // head-major: pixel stride is 32 fp16 (64B)
        const _Float16* vl = vproj + ((size_t)(h * 2 + b) * PTOT + PLSTART[l]) * 32 + s * 8;

        // Phase 1: addresses + packed fp16 weights for all 4 taps of this level
        const _Float16* pp[4];
        f16x2 hw[4][4];
#pragma unroll
        for (int p = 0; p < 4; ++p) {
            const int t = l * 4 + p;
            f32x2 o2 = bfpair(off16[t]);
            float x = fminf(fmaxf(xb + o2.x, 0.f), (float)(W + 1));
            float y = fminf(fmaxf(yb + o2.y, 0.f), (float)(H + 1));
            float x0f = floorf(x), y0f = floorf(y);
            float lx = x - x0f, ly = y - y0f;
            int x0 = (int)x0f, y0 = (int)y0f;
            pp[p] = vl + (size_t)((y0 * Wp + x0) * 32);
            float aww = aw[t];
            float wx0 = 1.f - lx;
            float wy0 = (1.f - ly) * aww, wy1 = ly * aww;
            _Float16 h00 = (_Float16)(wx0 * wy0), h01 = (_Float16)(lx * wy0);
            _Float16 h10 = (_Float16)(wx0 * wy1), h11 = (_Float16)(lx * wy1);
            hw[p][0] = f16x2{h00, h00}; hw[p][1] = f16x2{h01, h01};
            hw[p][2] = f16x2{h10, h10}; hw[p][3] = f16x2{h11, h11};
        }

        // Phase 2: issue all 16 gathers (x-pairs are contiguous 128B regions)
        uint4 c[4][4];
#pragma unroll
        for (int p = 0; p < 4; ++p) {
            c[p][0] = *(const uint4*)(pp[p]);
            c[p][1] = *(const uint4*)(pp[p] + 32);
            c[p][2] = *(const uint4*)(pp[p] + Wp * 32);
            c[p][3] = *(const uint4*)(pp[p] + Wp * 32 + 32);
        }

        // Phase 3: packed fp16 FMAs
#pragma unroll
        for (int p = 0; p < 4; ++p)
#pragma unroll
            for (int cc = 0; cc < 4; ++cc) {
                acc0 += __builtin_bit_cast(f16x2, c[p][cc].x) * hw[p][cc];
                acc1 += __builtin_bit_cast(f16x2, c[p][cc].y) * hw[p][cc];
                acc2 += __builtin_bit_cast(f16x2, c[p][cc].z) * hw[p][cc];
                acc3 += __builtin_bit_cast(f16x2, c[p][cc].w) * hw[p][cc];
            }
    }

    if (alive) {
        bf16 ob[8];
        ob[0] = __float2bfloat16((float)acc0[0]);
        ob[1] = __float2bfloat16((float)acc0[1]);
        ob[2] = __float2bfloat16((float)acc1[0]);
        ob[3] = __float2bfloat16((float)acc1[1]);
        ob[4] = __float2bfloat16((float)acc2[0]);
        ob[5] = __float2bfloat16((float)acc2[1]);
        ob[6] = __float2bfloat16((float)acc3[0]);
        ob[7] = __float2bfloat16((float)acc3[1]);
        *(uint4*)(msda_out + (size_t)q * 384 + h * 32 + s * 8) = *(const uint4*)ob;
    }
}

// ---------------------------------------------------------------------------
extern "C" void kernel_launch(void* const* d_in, const int* in_sizes, int n_in,
                              void* d_out, int out_size, void* d_ws, size_t ws_size,
                              hipStream_t stream) {
    const float* query = (const float*)d_in[0];
    const float* value = (const float*)d_in[1];
    const float* refp  = (const float*)d_in[2];
    const float* W_so  = (const float*)d_in[3];
    const float* b_so  = (const float*)d_in[4];
    const float* W_aw  = (const float*)d_in[5];
    const float* b_aw  = (const float*)d_in[6];
    const float* W_vp  = (const float*)d_in[7];
    const float* b_vp  = (const float*)d_in[8];
    const float* W_op  = (const float*)d_in[9];
    const float* b_op  = (const float*)d_in[10];
    float* out = (float*)d_out;

    // Workspace:
    //   offawl : bf16 MROWS*384 (34.1 MB) [off|awl]; msda aliased over rows
    //   vproj  : fp16 16*PTOT*32 (24.3 MB) head-major zero-padded layout
    //   weights: Wt_cat 384*256, Wt_vp/Wt_op 256*256 bf16, bcat 384 f32
    bf16*     d_offawl = (bf16*)d_ws;
    _Float16* d_vproj  = (_Float16*)(d_offawl + (size_t)MROWS * 384);
    bf16*     d_wtcat  = (bf16*)(d_vproj + (size_t)16 * PTOT * 32);
    bf16*     d_wtvp   = d_wtcat + 384 * 256;
    bf16*     d_wtop   = d_wtvp + 256 * 256;
    float*    d_bcat   = (float*)(d_wtop + 256 * 256);

    prep_weights<<<384, 256, 0, stream>>>(W_vp, W_so, W_aw, W_op, b_so, b_aw,
                                          d_wtvp, d_wtcat, d_wtop, d_bcat);
    hipMemsetAsync(d_vproj, 0, (size_t)16 * PTOT * 32 * sizeof(_Float16), stream);

    gemm_producer<<<GX * 5, 256, 0, stream>>>(
        query, value, d_wtcat, d_wtvp, d_bcat, b_vp, d_offawl, d_vproj);

    msda_sample10<<<(MROWS + 7) / 8, 256, 0, stream>>>(
        d_vproj, d_offawl, refp, d_offawl);

    gemm_out<<<GX * 2, 256, 0, stream>>>(d_offawl, d_wtop, b_op, query, out);
}